// Round 1
// baseline (5160.782 us; speedup 1.0000x reference)
//
#include <hip/hip_runtime.h>
#include <cmath>

#define E_EDGES 800000
#define N_NODES 50000
#define BN_EPS 1e-5f

// ---- workspace layout (float offsets) ----
#define OFF_S1SUM 0
#define OFF_S1SQ 128
#define OFF_S2SUM 256
#define OFF_S2SQ 512
#define OFF_GS1SUM 768
#define OFF_GS1SQ 832
#define OFF_GS2SUM 896
#define OFF_GS2SQ 960
#define OFF_FS1SUM 1024
#define OFF_FS1SQ 1152
#define OFF_FS2SUM 1280
#define OFF_FS2SQ 1408
#define OFF_NODE 1536                          // node_acc [N,128]
#define OFF_TG2 (OFF_NODE + N_NODES * 128)     // tg2 [N,64]
#define OFF_TF1 (OFF_TG2 + N_NODES * 64)       // tf1 [N,128]
#define OFF_TF2 OFF_NODE                       // tf2 reuses node_acc region (node_acc dead after fuse1)

__device__ __forceinline__ float sigmoid_(float x) { return 1.0f / (1.0f + __expf(-x)); }
__device__ __forceinline__ float softplus_(float x) { return (x > 20.0f) ? x : log1pf(__expf(x)); }
__device__ __forceinline__ float silu_(float x) { return x / (1.0f + __expf(-x)); }

// ---------------- chem branch: edge kernels ----------------
// block = 256 threads, tile = 64 edges. 12500 blocks (exact).

// stage A: t1[64x128] = xT[34x64]^T @ w1[34x128]; thread owns 8 edges x 4 cols.
__device__ __forceinline__ void stageA(const float* xT, const float* __restrict__ w1,
                                       int c0, int e0, float acc[8][4]) {
#pragma unroll
  for (int i = 0; i < 8; i++)
#pragma unroll
    for (int j = 0; j < 4; j++) acc[i][j] = 0.0f;
#pragma unroll 2
  for (int k = 0; k < 34; k++) {
    float4 w = *(const float4*)(w1 + k * 128 + c0);     // wave-coalesced 512B row
    float4 xa = *(const float4*)(xT + k * 64 + e0);     // broadcast (same addr across lanes)
    float4 xb = *(const float4*)(xT + k * 64 + e0 + 4);
    float xe[8] = {xa.x, xa.y, xa.z, xa.w, xb.x, xb.y, xb.z, xb.w};
#pragma unroll
    for (int i = 0; i < 8; i++) {
      acc[i][0] = fmaf(xe[i], w.x, acc[i][0]);
      acc[i][1] = fmaf(xe[i], w.y, acc[i][1]);
      acc[i][2] = fmaf(xe[i], w.z, acc[i][2]);
      acc[i][3] = fmaf(xe[i], w.w, acc[i][3]);
    }
  }
}

// hS layout: row e = 128 floats, 16B chunk j stored at chunk (j ^ (e&31)) -> conflict-free
// for both transposed writes (stage A) and k-major float4 reads (stage B).
__device__ __forceinline__ int hs_addr(int e, int c4) {  // c4 = col/4 (chunk index)
  return e * 128 + ((c4 ^ (e & 31)) << 2);
}

// stage B: acc[4 edges][8 cols] over cols cb..cb+7, K=128 from swizzled hS.
__device__ __forceinline__ void stageB(const float* hS, const float* __restrict__ w2,
                                       int e0, int cb, float acc[4][8]) {
#pragma unroll
  for (int i = 0; i < 4; i++)
#pragma unroll
    for (int j = 0; j < 8; j++) acc[i][j] = 0.0f;
#pragma unroll 2
  for (int k0 = 0; k0 < 128; k0 += 4) {
    float hv[4][4];
#pragma unroll
    for (int i = 0; i < 4; i++) {
      int e = e0 + i;
      float4 t = *(const float4*)(hS + hs_addr(e, k0 >> 2));
      hv[i][0] = t.x; hv[i][1] = t.y; hv[i][2] = t.z; hv[i][3] = t.w;
    }
#pragma unroll
    for (int kk = 0; kk < 4; kk++) {
      float4 wA = *(const float4*)(w2 + (k0 + kk) * 256 + cb);
      float4 wB = *(const float4*)(w2 + (k0 + kk) * 256 + cb + 4);
      float wv[8] = {wA.x, wA.y, wA.z, wA.w, wB.x, wB.y, wB.z, wB.w};
#pragma unroll
      for (int i = 0; i < 4; i++) {
        float h = hv[i][kk];
#pragma unroll
        for (int j = 0; j < 8; j++) acc[i][j] = fmaf(h, wv[j], acc[i][j]);
      }
    }
  }
}

// per-chunk column stats reduction (sum, sumsq of t2 = acc + b2) into shared sh[0:256]/sh[256:512]
__device__ __forceinline__ void reduce_stats(const float acc[4][8], int cb,
                                             const float* __restrict__ b2, float* sh) {
  float4 bA = *(const float4*)(b2 + cb);
  float4 bB = *(const float4*)(b2 + cb + 4);
  float bb[8] = {bA.x, bA.y, bA.z, bA.w, bB.x, bB.y, bB.z, bB.w};
  float s[8], q[8];
#pragma unroll
  for (int j = 0; j < 8; j++) {
    s[j] = 0.0f; q[j] = 0.0f;
#pragma unroll
    for (int i = 0; i < 4; i++) {
      float v = acc[i][j] + bb[j];
      s[j] += v; q[j] += v * v;
    }
  }
#pragma unroll
  for (int off = 1; off < 16; off <<= 1) {
#pragma unroll
    for (int j = 0; j < 8; j++) {
      s[j] += __shfl_xor(s[j], off);
      q[j] += __shfl_xor(q[j], off);
    }
  }
  if ((threadIdx.x & 15) == 0) {
#pragma unroll
    for (int j = 0; j < 8; j++) {
      atomicAdd(&sh[cb + j], s[j]);
      atomicAdd(&sh[256 + cb + j], q[j]);
    }
  }
}

__global__ __launch_bounds__(256) void k_chem_stats1(const float* __restrict__ chem,
                                                     const float* __restrict__ w1,
                                                     const float* __restrict__ b1,
                                                     float* __restrict__ ws) {
  __shared__ float xT[34 * 64];
  __shared__ float s_sum[128], s_sq[128];
  const int t = threadIdx.x;
  const int e_base = blockIdx.x * 64;
  if (t < 128) { s_sum[t] = 0.0f; s_sq[t] = 0.0f; }
  for (int i = t; i < 34 * 64; i += 256)
    xT[(i % 34) * 64 + (i / 34)] = chem[e_base * 34 + i];  // fully coalesced global read
  __syncthreads();
  const int c0 = (t & 31) * 4, e0 = (t >> 5) * 8;
  float acc[8][4];
  stageA(xT, w1, c0, e0, acc);
  float4 bv = *(const float4*)(b1 + c0);
  float bb[4] = {bv.x, bv.y, bv.z, bv.w};
  float ps[4] = {0, 0, 0, 0}, pq[4] = {0, 0, 0, 0};
#pragma unroll
  for (int j = 0; j < 4; j++)
#pragma unroll
    for (int i = 0; i < 8; i++) {
      float v = acc[i][j] + bb[j];
      ps[j] += v; pq[j] += v * v;
    }
#pragma unroll
  for (int j = 0; j < 4; j++) {  // lanes l and l+32 share c0
    ps[j] += __shfl_down(ps[j], 32);
    pq[j] += __shfl_down(pq[j], 32);
  }
  if ((t & 63) < 32) {
#pragma unroll
    for (int j = 0; j < 4; j++) {
      atomicAdd(&s_sum[c0 + j], ps[j]);
      atomicAdd(&s_sq[c0 + j], pq[j]);
    }
  }
  __syncthreads();
  if (t < 128) {
    atomicAdd(&ws[OFF_S1SUM + t], s_sum[t]);
    atomicAdd(&ws[OFF_S1SQ + t], s_sq[t]);
  }
}

// MODE 2: accumulate BN2 batch stats of t2.  MODE 3: apply BN2, gate, scatter into nodes.
template <int MODE>
__global__ __launch_bounds__(256) void k_chem_main(
    const float* __restrict__ chem, const int* __restrict__ vids,
    const float* __restrict__ w1, const float* __restrict__ b1,
    const float* __restrict__ g1, const float* __restrict__ be1,
    const float* __restrict__ w2, const float* __restrict__ b2,
    const float* __restrict__ g2, const float* __restrict__ be2,
    float* __restrict__ ws) {
  __shared__ float xT[34 * 64];
  __shared__ float hS[64 * 128];
  __shared__ float A1[128], C1[128];
  __shared__ float sh2[512];  // MODE2: stats sums; MODE3: A2[0:256], C2[256:512]
  __shared__ int vidS[64];
  const int t = threadIdx.x;
  const int e_base = blockIdx.x * 64;
  const float invE = 1.0f / (float)E_EDGES;

  if (t < 128) {  // fold BN1: bn1(t1) = A1*accA + C1 (t1 = accA + b1)
    float s = ws[OFF_S1SUM + t], q = ws[OFF_S1SQ + t];
    float m = s * invE, v = q * invE - m * m;
    float a = g1[t] * rsqrtf(v + BN_EPS);
    A1[t] = a;
    C1[t] = a * (b1[t] - m) + be1[t];
  }
  if (MODE == 3) {
    if (t < 256) {
      float s = ws[OFF_S2SUM + t], q = ws[OFF_S2SQ + t];
      float m = s * invE, v = q * invE - m * m;
      float a = g2[t] * rsqrtf(v + BN_EPS);
      sh2[t] = a;
      sh2[256 + t] = a * (b2[t] - m) + be2[t];
    }
    if (t < 64) vidS[t] = vids[e_base + t];
  } else {
    if (t < 256) { sh2[t] = 0.0f; sh2[256 + t] = 0.0f; }
  }
  for (int i = t; i < 34 * 64; i += 256)
    xT[(i % 34) * 64 + (i / 34)] = chem[e_base * 34 + i];
  __syncthreads();

  {  // stage A + BN1 + SiLU -> swizzled hS
    const int c0 = (t & 31) * 4, e0 = (t >> 5) * 8;
    float acc[8][4];
    stageA(xT, w1, c0, e0, acc);
    float a1[4] = {A1[c0], A1[c0 + 1], A1[c0 + 2], A1[c0 + 3]};
    float c1[4] = {C1[c0], C1[c0 + 1], C1[c0 + 2], C1[c0 + 3]};
#pragma unroll
    for (int i = 0; i < 8; i++) {
      int e = e0 + i;
      float4 hv;
      hv.x = silu_(fmaf(a1[0], acc[i][0], c1[0]));
      hv.y = silu_(fmaf(a1[1], acc[i][1], c1[1]));
      hv.z = silu_(fmaf(a1[2], acc[i][2], c1[2]));
      hv.w = silu_(fmaf(a1[3], acc[i][3], c1[3]));
      *(float4*)(hS + hs_addr(e, c0 >> 2)) = hv;
    }
  }
  __syncthreads();

  const int e0 = (t & 15) * 4, cg = (t >> 4) * 8;
  float accF[4][8];  // cols cg..cg+7   (filter half in MODE 3)
  stageB(hS, w2, e0, cg, accF);
  if (MODE == 2) reduce_stats(accF, cg, b2, sh2);
  float accC[4][8];  // cols 128+cg..   (core half)
  stageB(hS, w2, e0, 128 + cg, accC);
  if (MODE == 2) {
    reduce_stats(accC, 128 + cg, b2, sh2);
    __syncthreads();
    if (t < 256) {
      atomicAdd(ws + OFF_S2SUM + t, sh2[t]);
      atomicAdd(ws + OFF_S2SQ + t, sh2[256 + t]);
    }
  }
  if (MODE == 3) {
    float aF[8], cF[8], aC[8], cC[8];
#pragma unroll
    for (int j = 0; j < 8; j++) {
      aF[j] = sh2[cg + j];        cF[j] = sh2[256 + cg + j];
      aC[j] = sh2[128 + cg + j];  cC[j] = sh2[256 + 128 + cg + j];
    }
#pragma unroll
    for (int i = 0; i < 4; i++) {
      int vid = vidS[e0 + i];
      float* dst = ws + OFF_NODE + (size_t)vid * 128 + cg;
#pragma unroll
      for (int j = 0; j < 8; j++) {
        float F = fmaf(aF[j], accF[i][j], cF[j]);
        float Co = fmaf(aC[j], accC[i][j], cC[j]);
        atomicAdd(dst + j, sigmoid_(F) * softplus_(Co));
      }
    }
  }
}

// ---------------- geom / fuse: wave-per-node kernels (block=256 -> 16 nodes) ----------------
__device__ __forceinline__ float geom_tg1(const float* __restrict__ geom,
                                          const float* __restrict__ wg1,
                                          float bcol, int n, int lane) {
  float x = (lane < 48) ? geom[n * 48 + lane] : 0.0f;
  float acc = bcol;
#pragma unroll
  for (int k = 0; k < 48; k++) {
    float xk = __shfl(x, k);
    acc = fmaf(xk, wg1[k * 64 + lane], acc);
  }
  return acc;
}

__global__ __launch_bounds__(256) void k_geom_stats1(const float* __restrict__ geom,
                                                     const float* __restrict__ wg1,
                                                     const float* __restrict__ bg1,
                                                     float* __restrict__ ws) {
  __shared__ float ssum[64], ssq[64];
  const int t = threadIdx.x, lane = t & 63, w = t >> 6;
  if (t < 64) { ssum[t] = 0.0f; ssq[t] = 0.0f; }
  __syncthreads();
  const float bcol = bg1[lane];
  float bs = 0.0f, bq = 0.0f;
  const int nb = blockIdx.x * 16 + w * 4;
  for (int u = 0; u < 4; u++) {
    float acc = geom_tg1(geom, wg1, bcol, nb + u, lane);
    bs += acc; bq += acc * acc;
  }
  atomicAdd(&ssum[lane], bs);
  atomicAdd(&ssq[lane], bq);
  __syncthreads();
  if (t < 64) {
    atomicAdd(ws + OFF_GS1SUM + t, ssum[t]);
    atomicAdd(ws + OFF_GS1SQ + t, ssq[t]);
  }
}

__global__ __launch_bounds__(256) void k_geom_main(
    const float* __restrict__ geom, const float* __restrict__ wg1,
    const float* __restrict__ bg1, const float* __restrict__ gg1,
    const float* __restrict__ beg1, const float* __restrict__ wg2,
    const float* __restrict__ bg2, float* __restrict__ ws) {
  __shared__ float ssum[64], ssq[64];
  const int t = threadIdx.x, lane = t & 63, w = t >> 6;
  if (t < 64) { ssum[t] = 0.0f; ssq[t] = 0.0f; }
  const float invN = 1.0f / (float)N_NODES;
  float s1 = ws[OFF_GS1SUM + lane], q1 = ws[OFF_GS1SQ + lane];
  float m1 = s1 * invN, v1 = q1 * invN - m1 * m1;
  float a1 = gg1[lane] * rsqrtf(v1 + BN_EPS);
  float c1 = beg1[lane] - a1 * m1;
  const float bcol = bg1[lane], b2col = bg2[lane];
  __syncthreads();
  float bs = 0.0f, bq = 0.0f;
  const int nb = blockIdx.x * 16 + w * 4;
  for (int u = 0; u < 4; u++) {
    int n = nb + u;
    float tg1 = geom_tg1(geom, wg1, bcol, n, lane);
    float hg = silu_(fmaf(a1, tg1, c1));
    float acc = b2col;
#pragma unroll
    for (int k = 0; k < 64; k++) {
      float hk = __shfl(hg, k);
      acc = fmaf(hk, wg2[k * 64 + lane], acc);
    }
    ws[OFF_TG2 + n * 64 + lane] = acc;  // raw tg2; BN applied in fuse1
    bs += acc; bq += acc * acc;
  }
  atomicAdd(&ssum[lane], bs);
  atomicAdd(&ssq[lane], bq);
  __syncthreads();
  if (t < 64) {
    atomicAdd(ws + OFF_GS2SUM + t, ssum[t]);
    atomicAdd(ws + OFF_GS2SQ + t, ssq[t]);
  }
}

__global__ __launch_bounds__(256) void k_fuse1(const float* __restrict__ wf1,
                                               const float* __restrict__ bf1,
                                               const float* __restrict__ gg2,
                                               const float* __restrict__ beg2,
                                               float* __restrict__ ws) {
  __shared__ float ssum[128], ssq[128];
  const int t = threadIdx.x, lane = t & 63, w = t >> 6;
  if (t < 128) { ssum[t] = 0.0f; ssq[t] = 0.0f; }
  const float invN = 1.0f / (float)N_NODES;
  float s2 = ws[OFF_GS2SUM + lane], q2 = ws[OFF_GS2SQ + lane];
  float mg = s2 * invN, vg = q2 * invN - mg * mg;
  float ag = gg2[lane] * rsqrtf(vg + BN_EPS);
  float cg_ = beg2[lane] - ag * mg;
  const float bA = bf1[lane], bB = bf1[64 + lane];
  __syncthreads();
  float sA = 0, qA = 0, sB = 0, qB = 0;
  const int nb = blockIdx.x * 16 + w * 4;
  for (int u = 0; u < 4; u++) {
    int n = nb + u;
    float xa = ws[OFF_NODE + n * 128 + lane];
    float xb = ws[OFF_NODE + n * 128 + 64 + lane];
    float xg = fmaf(ag, ws[OFF_TG2 + n * 64 + lane], cg_);
    float acc1 = bA, acc2 = bB;
#pragma unroll
    for (int k = 0; k < 64; k++) {
      float xk = __shfl(xa, k);
      acc1 = fmaf(xk, wf1[k * 128 + lane], acc1);
      acc2 = fmaf(xk, wf1[k * 128 + 64 + lane], acc2);
    }
#pragma unroll
    for (int k = 0; k < 64; k++) {
      float xk = __shfl(xb, k);
      acc1 = fmaf(xk, wf1[(64 + k) * 128 + lane], acc1);
      acc2 = fmaf(xk, wf1[(64 + k) * 128 + 64 + lane], acc2);
    }
#pragma unroll
    for (int k = 0; k < 64; k++) {
      float xk = __shfl(xg, k);
      acc1 = fmaf(xk, wf1[(128 + k) * 128 + lane], acc1);
      acc2 = fmaf(xk, wf1[(128 + k) * 128 + 64 + lane], acc2);
    }
    ws[OFF_TF1 + n * 128 + lane] = acc1;
    ws[OFF_TF1 + n * 128 + 64 + lane] = acc2;
    sA += acc1; qA += acc1 * acc1;
    sB += acc2; qB += acc2 * acc2;
  }
  atomicAdd(&ssum[lane], sA); atomicAdd(&ssq[lane], qA);
  atomicAdd(&ssum[64 + lane], sB); atomicAdd(&ssq[64 + lane], qB);
  __syncthreads();
  if (t < 128) {
    atomicAdd(ws + OFF_FS1SUM + t, ssum[t]);
    atomicAdd(ws + OFF_FS1SQ + t, ssq[t]);
  }
}

__global__ __launch_bounds__(256) void k_fuse2(const float* __restrict__ wf2,
                                               const float* __restrict__ bf2,
                                               const float* __restrict__ gf1,
                                               const float* __restrict__ bef1,
                                               float* __restrict__ ws) {
  __shared__ float ssum[128], ssq[128];
  const int t = threadIdx.x, lane = t & 63, w = t >> 6;
  if (t < 128) { ssum[t] = 0.0f; ssq[t] = 0.0f; }
  const float invN = 1.0f / (float)N_NODES;
  float sA_ = ws[OFF_FS1SUM + lane], qA_ = ws[OFF_FS1SQ + lane];
  float mA = sA_ * invN, vA = qA_ * invN - mA * mA;
  float aA = gf1[lane] * rsqrtf(vA + BN_EPS);
  float cA = bef1[lane] - aA * mA;
  float sB_ = ws[OFF_FS1SUM + 64 + lane], qB_ = ws[OFF_FS1SQ + 64 + lane];
  float mB = sB_ * invN, vB = qB_ * invN - mB * mB;
  float aB = gf1[64 + lane] * rsqrtf(vB + BN_EPS);
  float cB = bef1[64 + lane] - aB * mB;
  const float b1c = bf2[lane], b2c = bf2[64 + lane];
  __syncthreads();
  float sA = 0, qA = 0, sB = 0, qB = 0;
  const int nb = blockIdx.x * 16 + w * 4;
  for (int u = 0; u < 4; u++) {
    int n = nb + u;
    float ha = silu_(fmaf(aA, ws[OFF_TF1 + n * 128 + lane], cA));
    float hb = silu_(fmaf(aB, ws[OFF_TF1 + n * 128 + 64 + lane], cB));
    float acc1 = b1c, acc2 = b2c;
#pragma unroll
    for (int k = 0; k < 64; k++) {
      float hk = __shfl(ha, k);
      acc1 = fmaf(hk, wf2[k * 128 + lane], acc1);
      acc2 = fmaf(hk, wf2[k * 128 + 64 + lane], acc2);
    }
#pragma unroll
    for (int k = 0; k < 64; k++) {
      float hk = __shfl(hb, k);
      acc1 = fmaf(hk, wf2[(64 + k) * 128 + lane], acc1);
      acc2 = fmaf(hk, wf2[(64 + k) * 128 + 64 + lane], acc2);
    }
    ws[OFF_TF2 + n * 128 + lane] = acc1;   // overwrites node_acc (dead after fuse1)
    ws[OFF_TF2 + n * 128 + 64 + lane] = acc2;
    sA += acc1; qA += acc1 * acc1;
    sB += acc2; qB += acc2 * acc2;
  }
  atomicAdd(&ssum[lane], sA); atomicAdd(&ssq[lane], qA);
  atomicAdd(&ssum[64 + lane], sB); atomicAdd(&ssq[64 + lane], qB);
  __syncthreads();
  if (t < 128) {
    atomicAdd(ws + OFF_FS2SUM + t, ssum[t]);
    atomicAdd(ws + OFF_FS2SQ + t, ssq[t]);
  }
}

__global__ __launch_bounds__(256) void k_final(const float* __restrict__ gf2,
                                               const float* __restrict__ bef2,
                                               const float* __restrict__ ws,
                                               float* __restrict__ out) {
  const int idx = blockIdx.x * 256 + threadIdx.x;
  const int base = idx * 4;
  if (base >= N_NODES * 128) return;
  const float invN = 1.0f / (float)N_NODES;
  const int c0 = base & 127;
  float4 v = *(const float4*)(ws + OFF_TF2 + base);
  float vv[4] = {v.x, v.y, v.z, v.w}, r[4];
#pragma unroll
  for (int j = 0; j < 4; j++) {
    int c = c0 + j;
    float s = ws[OFF_FS2SUM + c], q = ws[OFF_FS2SQ + c];
    float m = s * invN, var = q * invN - m * m;
    float a = gf2[c] * rsqrtf(var + BN_EPS);
    r[j] = fmaf(a, vv[j] - m, bef2[c]);
  }
  *(float4*)(out + base) = make_float4(r[0], r[1], r[2], r[3]);
}

extern "C" void kernel_launch(void* const* d_in, const int* in_sizes, int n_in,
                              void* d_out, int out_size, void* d_ws, size_t ws_size,
                              hipStream_t stream) {
  const float* chem = (const float*)d_in[0];
  const float* geom = (const float*)d_in[1];
  const int* vids = (const int*)d_in[2];
  const float* w_c1 = (const float*)d_in[3];  const float* b_c1 = (const float*)d_in[4];
  const float* g_c1 = (const float*)d_in[5];  const float* be_c1 = (const float*)d_in[6];
  const float* w_c2 = (const float*)d_in[7];  const float* b_c2 = (const float*)d_in[8];
  const float* g_c2 = (const float*)d_in[9];  const float* be_c2 = (const float*)d_in[10];
  const float* w_g1 = (const float*)d_in[11]; const float* b_g1 = (const float*)d_in[12];
  const float* g_g1 = (const float*)d_in[13]; const float* be_g1 = (const float*)d_in[14];
  const float* w_g2 = (const float*)d_in[15]; const float* b_g2 = (const float*)d_in[16];
  const float* g_g2 = (const float*)d_in[17]; const float* be_g2 = (const float*)d_in[18];
  const float* w_f1 = (const float*)d_in[19]; const float* b_f1 = (const float*)d_in[20];
  const float* g_f1 = (const float*)d_in[21]; const float* be_f1 = (const float*)d_in[22];
  const float* w_f2 = (const float*)d_in[23]; const float* b_f2 = (const float*)d_in[24];
  const float* g_f2 = (const float*)d_in[25]; const float* be_f2 = (const float*)d_in[26];
  float* ws = (float*)d_ws;
  float* out = (float*)d_out;

  // zero stats + node accumulator (ws is poisoned 0xAA before every launch)
  hipMemsetAsync(d_ws, 0, (size_t)(OFF_NODE + N_NODES * 128) * sizeof(float), stream);

  k_chem_stats1<<<dim3(12500), dim3(256), 0, stream>>>(chem, w_c1, b_c1, ws);
  k_chem_main<2><<<dim3(12500), dim3(256), 0, stream>>>(chem, vids, w_c1, b_c1, g_c1, be_c1,
                                                        w_c2, b_c2, g_c2, be_c2, ws);
  k_geom_stats1<<<dim3(3125), dim3(256), 0, stream>>>(geom, w_g1, b_g1, ws);
  k_geom_main<<<dim3(3125), dim3(256), 0, stream>>>(geom, w_g1, b_g1, g_g1, be_g1, w_g2, b_g2, ws);
  k_chem_main<3><<<dim3(12500), dim3(256), 0, stream>>>(chem, vids, w_c1, b_c1, g_c1, be_c1,
                                                        w_c2, b_c2, g_c2, be_c2, ws);
  k_fuse1<<<dim3(3125), dim3(256), 0, stream>>>(w_f1, b_f1, g_g2, be_g2, ws);
  k_fuse2<<<dim3(3125), dim3(256), 0, stream>>>(w_f2, b_f2, g_f1, be_f1, ws);
  k_final<<<dim3(6250), dim3(256), 0, stream>>>(g_f2, be_f2, ws, out);
}

// Round 2
// 2500.617 us; speedup vs baseline: 2.0638x; 2.0638x over previous
//
#include <hip/hip_runtime.h>
#include <hip/hip_bf16.h>
#include <cmath>

#define E_EDGES 800000
#define N_NODES 50000
#define BN_EPS 1e-5f

typedef __attribute__((ext_vector_type(8))) short short8;
typedef __attribute__((ext_vector_type(4))) float float4v;
typedef unsigned short ushort_t;

// ---- workspace layout (float offsets) ----
#define OFF_S1SUM 0
#define OFF_S1SQ 128
#define OFF_S2SUM 256
#define OFF_S2SQ 512
#define OFF_GS1SUM 768
#define OFF_GS1SQ 832
#define OFF_GS2SUM 896
#define OFF_GS2SQ 960
#define OFF_FS1SUM 1024
#define OFF_FS1SQ 1152
#define OFF_FS2SUM 1280
#define OFF_FS2SQ 1408
#define OFF_NODE 1536                          // node_acc [N,128]
#define OFF_TG2 (OFF_NODE + N_NODES * 128)     // tg2 [N,64]
#define OFF_TF1 (OFF_TG2 + N_NODES * 64)       // tf1 [N,128]
#define OFF_TF2 OFF_NODE                       // tf2 reuses node_acc (dead after fuse1)
#define OFF_W1T (OFF_TF1 + N_NODES * 128)      // w1T bf16 [128][64]  (4096 floats)
#define OFF_W2T (OFF_W1T + 4096)               // w2T bf16 [256][128] (16384 floats)

__device__ __forceinline__ float sigmoid_(float x) { return 1.0f / (1.0f + __expf(-x)); }
__device__ __forceinline__ float softplus_(float x) { return (x > 20.0f) ? x : log1pf(__expf(x)); }
__device__ __forceinline__ float silu_(float x) { return x / (1.0f + __expf(-x)); }

__device__ __forceinline__ ushort_t f2bf(float f) {
  __hip_bfloat16 h = __float2bfloat16(f);
  return *(ushort_t*)&h;
}

// ---------------- prep: transpose+convert weights to bf16 in ws ----------------
__global__ __launch_bounds__(256) void k_prep(const float* __restrict__ w1,
                                              const float* __restrict__ w2,
                                              float* __restrict__ ws) {
  ushort_t* w1t = (ushort_t*)(ws + OFF_W1T);
  ushort_t* w2t = (ushort_t*)(ws + OFF_W2T);
  int idx = blockIdx.x * 256 + threadIdx.x;
  if (idx < 128 * 64) {  // w1T[c][k], K padded 34 -> 64 with zeros
    int c = idx >> 6, k = idx & 63;
    float v = (k < 34) ? w1[k * 128 + c] : 0.0f;
    w1t[idx] = f2bf(v);
  }
  int j = idx - 128 * 64;
  if (j >= 0 && j < 256 * 128) {  // w2T[c][k]
    int c = j >> 7, k = j & 127;
    w2t[j] = f2bf(w2[k * 256 + c]);
  }
}

// ---------------- chem branch: one templated kernel, 3 passes ----------------
// block = 256 threads (4 waves), 64-edge tile, 12500 blocks.
// MODE 1: t1 batch stats.  MODE 2: t2 batch stats.  MODE 3: gate + scatter.
// MFMA 16x16x32 bf16. A-frag: A[m=lane&15][k=quad*8+j]. B-frag: B[k=quad*8+j][n=lane&15].
// C/D: col=lane&15, row=quad*4+reg.
template <int MODE>
__global__ __launch_bounds__(256) void k_chem(
    const float* __restrict__ chem, const int* __restrict__ vids,
    const float* __restrict__ b1, const float* __restrict__ g1, const float* __restrict__ be1,
    const float* __restrict__ b2, const float* __restrict__ g2, const float* __restrict__ be2,
    float* __restrict__ ws) {
  __shared__ ushort_t xB[64 * 72];   // x tile bf16, K padded to 64, row stride 72 (bank-walk 4e mod 32)
  __shared__ ushort_t hS[64 * 136];  // h tile bf16, row stride 136
  __shared__ float A1[128], C1[128];
  __shared__ float sh2[512];         // MODE2: col sums/sq of t2; MODE3: A2[0:256], C2[256:512]
  __shared__ float sSum[128], sSq[128];  // MODE1 t1 stats
  __shared__ int vidS[64];

  const int t = threadIdx.x;
  const int e_base = blockIdx.x * 64;
  const int wv = t >> 6, ln = t & 63, r15 = ln & 15, qd = ln >> 4;
  const float invE = 1.0f / (float)E_EDGES;
  const ushort_t* w1t = (const ushort_t*)(ws + OFF_W1T);
  const ushort_t* w2t = (const ushort_t*)(ws + OFF_W2T);

  // ---- phase 1: zero xB, compute per-kernel BN affines / zero stats ----
  {
    int* p = (int*)xB;
#pragma unroll
    for (int i = t; i < 64 * 72 / 2; i += 256) p[i] = 0;
  }
  if (MODE == 1) {
    if (t < 128) { sSum[t] = 0.0f; sSq[t] = 0.0f; }
  } else {
    if (t < 128) {  // fold BN1: bn1(t1) = A1*acc + C1  (t1 = acc + b1; stats incl. bias)
      float s = ws[OFF_S1SUM + t], q = ws[OFF_S1SQ + t];
      float m = s * invE, v = q * invE - m * m;
      float a = g1[t] * rsqrtf(v + BN_EPS);
      A1[t] = a;
      C1[t] = a * (b1[t] - m) + be1[t];
    }
    if (MODE == 2) {
      sh2[t] = 0.0f; sh2[256 + t] = 0.0f;
    } else {  // MODE 3: fold BN2
      float s = ws[OFF_S2SUM + t], q = ws[OFF_S2SQ + t];
      float m = s * invE, v = q * invE - m * m;
      float a = g2[t] * rsqrtf(v + BN_EPS);
      sh2[t] = a;
      sh2[256 + t] = a * (b2[t] - m) + be2[t];
      if (t < 64) vidS[t] = vids[e_base + t];
    }
  }
  __syncthreads();

  // ---- phase 2: fill xB (coalesced fp32 read -> bf16) ----
  for (int i = t; i < 64 * 34; i += 256) {
    int e = i / 34, k = i - e * 34;
    xB[e * 72 + k] = f2bf(chem[e_base * 34 + i]);
  }
  __syncthreads();

  // ---- stage A: t1[64x128] = x @ w1 via MFMA; wave wv owns edges 16wv..16wv+15 ----
  short8 xa0 = *(const short8*)&xB[(16 * wv + r15) * 72 + 8 * qd];
  short8 xa1 = *(const short8*)&xB[(16 * wv + r15) * 72 + 32 + 8 * qd];
#pragma unroll
  for (int t8 = 0; t8 < 8; ++t8) {
    const int col = 16 * t8 + r15;
    short8 wb0 = *(const short8*)&w1t[col * 64 + 8 * qd];
    short8 wb1 = *(const short8*)&w1t[col * 64 + 32 + 8 * qd];
    float4v acc = {0.0f, 0.0f, 0.0f, 0.0f};
    acc = __builtin_amdgcn_mfma_f32_16x16x32_bf16(xa0, wb0, acc, 0, 0, 0);
    acc = __builtin_amdgcn_mfma_f32_16x16x32_bf16(xa1, wb1, acc, 0, 0, 0);
    if (MODE == 1) {
      float b = b1[col];
      float s = 0.0f, q = 0.0f;
#pragma unroll
      for (int r = 0; r < 4; ++r) {
        float v = acc[r] + b;
        s += v; q += v * v;
      }
      s += __shfl_xor(s, 16); q += __shfl_xor(q, 16);
      s += __shfl_xor(s, 32); q += __shfl_xor(q, 32);
      if (ln < 16) { atomicAdd(&sSum[col], s); atomicAdd(&sSq[col], q); }
    } else {
      float a1c = A1[col], c1c = C1[col];
#pragma unroll
      for (int r = 0; r < 4; ++r) {
        float hv = silu_(fmaf(a1c, acc[r], c1c));
        hS[(16 * wv + 4 * qd + r) * 136 + col] = f2bf(hv);
      }
    }
  }

  if (MODE == 1) {
    __syncthreads();
    if (t < 128) {
      atomicAdd(ws + OFF_S1SUM + t, sSum[t]);
      atomicAdd(ws + OFF_S1SQ + t, sSq[t]);
    }
    return;
  }

  // ---- stage B: t2[64x256] = h @ w2 via MFMA (wave reads only its own rows; no barrier) ----
  short8 ha[4];
#pragma unroll
  for (int ks = 0; ks < 4; ++ks)
    ha[ks] = *(const short8*)&hS[(16 * wv + r15) * 136 + ks * 32 + 8 * qd];

#pragma unroll 2
  for (int t8 = 0; t8 < 8; ++t8) {
    const int colF = 16 * t8 + r15;  // filter col; core col = 128 + colF
    float4v aF = {0.0f, 0.0f, 0.0f, 0.0f};
    float4v aC = {0.0f, 0.0f, 0.0f, 0.0f};
#pragma unroll
    for (int ks = 0; ks < 4; ++ks) {
      short8 bF = *(const short8*)&w2t[colF * 128 + ks * 32 + 8 * qd];
      short8 bC = *(const short8*)&w2t[(128 + colF) * 128 + ks * 32 + 8 * qd];
      aF = __builtin_amdgcn_mfma_f32_16x16x32_bf16(ha[ks], bF, aF, 0, 0, 0);
      aC = __builtin_amdgcn_mfma_f32_16x16x32_bf16(ha[ks], bC, aC, 0, 0, 0);
    }
    if (MODE == 2) {
      float bF = b2[colF], bC = b2[128 + colF];
      float sF = 0, qF = 0, sC = 0, qC = 0;
#pragma unroll
      for (int r = 0; r < 4; ++r) {
        float vF = aF[r] + bF, vC = aC[r] + bC;
        sF += vF; qF += vF * vF; sC += vC; qC += vC * vC;
      }
      sF += __shfl_xor(sF, 16); qF += __shfl_xor(qF, 16);
      sF += __shfl_xor(sF, 32); qF += __shfl_xor(qF, 32);
      sC += __shfl_xor(sC, 16); qC += __shfl_xor(qC, 16);
      sC += __shfl_xor(sC, 32); qC += __shfl_xor(qC, 32);
      if (ln < 16) {
        atomicAdd(&sh2[colF], sF); atomicAdd(&sh2[256 + colF], qF);
        atomicAdd(&sh2[128 + colF], sC); atomicAdd(&sh2[384 + colF], qC);
      }
    } else {  // MODE 3: BN2 + gate + scatter. 16-lane groups hit 16 consecutive cols of ONE vid
      float aF2 = sh2[colF], cF2 = sh2[256 + colF];
      float aC2 = sh2[128 + colF], cC2 = sh2[384 + colF];
#pragma unroll
      for (int r = 0; r < 4; ++r) {
        float F = fmaf(aF2, aF[r], cF2);
        float Co = fmaf(aC2, aC[r], cC2);
        float g = sigmoid_(F) * softplus_(Co);
        int e = 16 * wv + 4 * qd + r;
        atomicAdd(ws + OFF_NODE + (size_t)vidS[e] * 128 + colF, g);
      }
    }
  }

  if (MODE == 2) {
    __syncthreads();
    if (t < 256) {
      atomicAdd(ws + OFF_S2SUM + t, sh2[t]);
      atomicAdd(ws + OFF_S2SQ + t, sh2[256 + t]);
    }
  }
}

// ---------------- geom / fuse: wave-per-node kernels (block=256 -> 16 nodes) ----------------
__device__ __forceinline__ float geom_tg1(const float* __restrict__ geom,
                                          const float* __restrict__ wg1,
                                          float bcol, int n, int lane) {
  float x = (lane < 48) ? geom[n * 48 + lane] : 0.0f;
  float acc = bcol;
#pragma unroll
  for (int k = 0; k < 48; k++) {
    float xk = __shfl(x, k);
    acc = fmaf(xk, wg1[k * 64 + lane], acc);
  }
  return acc;
}

__global__ __launch_bounds__(256) void k_geom_stats1(const float* __restrict__ geom,
                                                     const float* __restrict__ wg1,
                                                     const float* __restrict__ bg1,
                                                     float* __restrict__ ws) {
  __shared__ float ssum[64], ssq[64];
  const int t = threadIdx.x, lane = t & 63, w = t >> 6;
  if (t < 64) { ssum[t] = 0.0f; ssq[t] = 0.0f; }
  __syncthreads();
  const float bcol = bg1[lane];
  float bs = 0.0f, bq = 0.0f;
  const int nb = blockIdx.x * 16 + w * 4;
  for (int u = 0; u < 4; u++) {
    float acc = geom_tg1(geom, wg1, bcol, nb + u, lane);
    bs += acc; bq += acc * acc;
  }
  atomicAdd(&ssum[lane], bs);
  atomicAdd(&ssq[lane], bq);
  __syncthreads();
  if (t < 64) {
    atomicAdd(ws + OFF_GS1SUM + t, ssum[t]);
    atomicAdd(ws + OFF_GS1SQ + t, ssq[t]);
  }
}

__global__ __launch_bounds__(256) void k_geom_main(
    const float* __restrict__ geom, const float* __restrict__ wg1,
    const float* __restrict__ bg1, const float* __restrict__ gg1,
    const float* __restrict__ beg1, const float* __restrict__ wg2,
    const float* __restrict__ bg2, float* __restrict__ ws) {
  __shared__ float ssum[64], ssq[64];
  const int t = threadIdx.x, lane = t & 63, w = t >> 6;
  if (t < 64) { ssum[t] = 0.0f; ssq[t] = 0.0f; }
  const float invN = 1.0f / (float)N_NODES;
  float s1 = ws[OFF_GS1SUM + lane], q1 = ws[OFF_GS1SQ + lane];
  float m1 = s1 * invN, v1 = q1 * invN - m1 * m1;
  float a1 = gg1[lane] * rsqrtf(v1 + BN_EPS);
  float c1 = beg1[lane] - a1 * m1;
  const float bcol = bg1[lane], b2col = bg2[lane];
  __syncthreads();
  float bs = 0.0f, bq = 0.0f;
  const int nb = blockIdx.x * 16 + w * 4;
  for (int u = 0; u < 4; u++) {
    int n = nb + u;
    float tg1 = geom_tg1(geom, wg1, bcol, n, lane);
    float hg = silu_(fmaf(a1, tg1, c1));
    float acc = b2col;
#pragma unroll
    for (int k = 0; k < 64; k++) {
      float hk = __shfl(hg, k);
      acc = fmaf(hk, wg2[k * 64 + lane], acc);
    }
    ws[OFF_TG2 + n * 64 + lane] = acc;  // raw tg2; BN applied in fuse1
    bs += acc; bq += acc * acc;
  }
  atomicAdd(&ssum[lane], bs);
  atomicAdd(&ssq[lane], bq);
  __syncthreads();
  if (t < 64) {
    atomicAdd(ws + OFF_GS2SUM + t, ssum[t]);
    atomicAdd(ws + OFF_GS2SQ + t, ssq[t]);
  }
}

__global__ __launch_bounds__(256) void k_fuse1(const float* __restrict__ wf1,
                                               const float* __restrict__ bf1,
                                               const float* __restrict__ gg2,
                                               const float* __restrict__ beg2,
                                               float* __restrict__ ws) {
  __shared__ float ssum[128], ssq[128];
  const int t = threadIdx.x, lane = t & 63, w = t >> 6;
  if (t < 128) { ssum[t] = 0.0f; ssq[t] = 0.0f; }
  const float invN = 1.0f / (float)N_NODES;
  float s2 = ws[OFF_GS2SUM + lane], q2 = ws[OFF_GS2SQ + lane];
  float mg = s2 * invN, vg = q2 * invN - mg * mg;
  float ag = gg2[lane] * rsqrtf(vg + BN_EPS);
  float cg_ = beg2[lane] - ag * mg;
  const float bA = bf1[lane], bB = bf1[64 + lane];
  __syncthreads();
  float sA = 0, qA = 0, sB = 0, qB = 0;
  const int nb = blockIdx.x * 16 + w * 4;
  for (int u = 0; u < 4; u++) {
    int n = nb + u;
    float xa = ws[OFF_NODE + n * 128 + lane];
    float xb = ws[OFF_NODE + n * 128 + 64 + lane];
    float xg = fmaf(ag, ws[OFF_TG2 + n * 64 + lane], cg_);
    float acc1 = bA, acc2 = bB;
#pragma unroll
    for (int k = 0; k < 64; k++) {
      float xk = __shfl(xa, k);
      acc1 = fmaf(xk, wf1[k * 128 + lane], acc1);
      acc2 = fmaf(xk, wf1[k * 128 + 64 + lane], acc2);
    }
#pragma unroll
    for (int k = 0; k < 64; k++) {
      float xk = __shfl(xb, k);
      acc1 = fmaf(xk, wf1[(64 + k) * 128 + lane], acc1);
      acc2 = fmaf(xk, wf1[(64 + k) * 128 + 64 + lane], acc2);
    }
#pragma unroll
    for (int k = 0; k < 64; k++) {
      float xk = __shfl(xg, k);
      acc1 = fmaf(xk, wf1[(128 + k) * 128 + lane], acc1);
      acc2 = fmaf(xk, wf1[(128 + k) * 128 + 64 + lane], acc2);
    }
    ws[OFF_TF1 + n * 128 + lane] = acc1;
    ws[OFF_TF1 + n * 128 + 64 + lane] = acc2;
    sA += acc1; qA += acc1 * acc1;
    sB += acc2; qB += acc2 * acc2;
  }
  atomicAdd(&ssum[lane], sA); atomicAdd(&ssq[lane], qA);
  atomicAdd(&ssum[64 + lane], sB); atomicAdd(&ssq[64 + lane], qB);
  __syncthreads();
  if (t < 128) {
    atomicAdd(ws + OFF_FS1SUM + t, ssum[t]);
    atomicAdd(ws + OFF_FS1SQ + t, ssq[t]);
  }
}

__global__ __launch_bounds__(256) void k_fuse2(const float* __restrict__ wf2,
                                               const float* __restrict__ bf2,
                                               const float* __restrict__ gf1,
                                               const float* __restrict__ bef1,
                                               float* __restrict__ ws) {
  __shared__ float ssum[128], ssq[128];
  const int t = threadIdx.x, lane = t & 63, w = t >> 6;
  if (t < 128) { ssum[t] = 0.0f; ssq[t] = 0.0f; }
  const float invN = 1.0f / (float)N_NODES;
  float sA_ = ws[OFF_FS1SUM + lane], qA_ = ws[OFF_FS1SQ + lane];
  float mA = sA_ * invN, vA = qA_ * invN - mA * mA;
  float aA = gf1[lane] * rsqrtf(vA + BN_EPS);
  float cA = bef1[lane] - aA * mA;
  float sB_ = ws[OFF_FS1SUM + 64 + lane], qB_ = ws[OFF_FS1SQ + 64 + lane];
  float mB = sB_ * invN, vB = qB_ * invN - mB * mB;
  float aB = gf1[64 + lane] * rsqrtf(vB + BN_EPS);
  float cB = bef1[64 + lane] - aB * mB;
  const float b1c = bf2[lane], b2c = bf2[64 + lane];
  __syncthreads();
  float sA = 0, qA = 0, sB = 0, qB = 0;
  const int nb = blockIdx.x * 16 + w * 4;
  for (int u = 0; u < 4; u++) {
    int n = nb + u;
    float ha = silu_(fmaf(aA, ws[OFF_TF1 + n * 128 + lane], cA));
    float hb = silu_(fmaf(aB, ws[OFF_TF1 + n * 128 + 64 + lane], cB));
    float acc1 = b1c, acc2 = b2c;
#pragma unroll
    for (int k = 0; k < 64; k++) {
      float hk = __shfl(ha, k);
      acc1 = fmaf(hk, wf2[k * 128 + lane], acc1);
      acc2 = fmaf(hk, wf2[k * 128 + 64 + lane], acc2);
    }
#pragma unroll
    for (int k = 0; k < 64; k++) {
      float hk = __shfl(hb, k);
      acc1 = fmaf(hk, wf2[(64 + k) * 128 + lane], acc1);
      acc2 = fmaf(hk, wf2[(64 + k) * 128 + 64 + lane], acc2);
    }
    ws[OFF_TF2 + n * 128 + lane] = acc1;   // overwrites node_acc (dead after fuse1)
    ws[OFF_TF2 + n * 128 + 64 + lane] = acc2;
    sA += acc1; qA += acc1 * acc1;
    sB += acc2; qB += acc2 * acc2;
  }
  atomicAdd(&ssum[lane], sA); atomicAdd(&ssq[lane], qA);
  atomicAdd(&ssum[64 + lane], sB); atomicAdd(&ssq[64 + lane], qB);
  __syncthreads();
  if (t < 128) {
    atomicAdd(ws + OFF_FS2SUM + t, ssum[t]);
    atomicAdd(ws + OFF_FS2SQ + t, ssq[t]);
  }
}

__global__ __launch_bounds__(256) void k_final(const float* __restrict__ gf2,
                                               const float* __restrict__ bef2,
                                               const float* __restrict__ ws,
                                               float* __restrict__ out) {
  const int idx = blockIdx.x * 256 + threadIdx.x;
  const int base = idx * 4;
  if (base >= N_NODES * 128) return;
  const float invN = 1.0f / (float)N_NODES;
  const int c0 = base & 127;
  float4 v = *(const float4*)(ws + OFF_TF2 + base);
  float vv[4] = {v.x, v.y, v.z, v.w}, r[4];
#pragma unroll
  for (int j = 0; j < 4; j++) {
    int c = c0 + j;
    float s = ws[OFF_FS2SUM + c], q = ws[OFF_FS2SQ + c];
    float m = s * invN, var = q * invN - m * m;
    float a = gf2[c] * rsqrtf(var + BN_EPS);
    r[j] = fmaf(a, vv[j] - m, bef2[c]);
  }
  *(float4*)(out + base) = make_float4(r[0], r[1], r[2], r[3]);
}

extern "C" void kernel_launch(void* const* d_in, const int* in_sizes, int n_in,
                              void* d_out, int out_size, void* d_ws, size_t ws_size,
                              hipStream_t stream) {
  const float* chem = (const float*)d_in[0];
  const float* geom = (const float*)d_in[1];
  const int* vids = (const int*)d_in[2];
  const float* w_c1 = (const float*)d_in[3];  const float* b_c1 = (const float*)d_in[4];
  const float* g_c1 = (const float*)d_in[5];  const float* be_c1 = (const float*)d_in[6];
  const float* w_c2 = (const float*)d_in[7];  const float* b_c2 = (const float*)d_in[8];
  const float* g_c2 = (const float*)d_in[9];  const float* be_c2 = (const float*)d_in[10];
  const float* w_g1 = (const float*)d_in[11]; const float* b_g1 = (const float*)d_in[12];
  const float* g_g1 = (const float*)d_in[13]; const float* be_g1 = (const float*)d_in[14];
  const float* w_g2 = (const float*)d_in[15]; const float* b_g2 = (const float*)d_in[16];
  const float* g_g2 = (const float*)d_in[17]; const float* be_g2 = (const float*)d_in[18];
  const float* w_f1 = (const float*)d_in[19]; const float* b_f1 = (const float*)d_in[20];
  const float* g_f1 = (const float*)d_in[21]; const float* be_f1 = (const float*)d_in[22];
  const float* w_f2 = (const float*)d_in[23]; const float* b_f2 = (const float*)d_in[24];
  const float* g_f2 = (const float*)d_in[25]; const float* be_f2 = (const float*)d_in[26];
  float* ws = (float*)d_ws;
  float* out = (float*)d_out;

  // zero stats + node accumulator (ws is poisoned 0xAA before every launch)
  hipMemsetAsync(d_ws, 0, (size_t)(OFF_NODE + N_NODES * 128) * sizeof(float), stream);

  k_prep<<<dim3(160), dim3(256), 0, stream>>>(w_c1, w_c2, ws);
  k_chem<1><<<dim3(12500), dim3(256), 0, stream>>>(chem, vids, b_c1, g_c1, be_c1,
                                                   b_c2, g_c2, be_c2, ws);
  k_chem<2><<<dim3(12500), dim3(256), 0, stream>>>(chem, vids, b_c1, g_c1, be_c1,
                                                   b_c2, g_c2, be_c2, ws);
  k_geom_stats1<<<dim3(3125), dim3(256), 0, stream>>>(geom, w_g1, b_g1, ws);
  k_geom_main<<<dim3(3125), dim3(256), 0, stream>>>(geom, w_g1, b_g1, g_g1, be_g1, w_g2, b_g2, ws);
  k_chem<3><<<dim3(12500), dim3(256), 0, stream>>>(chem, vids, b_c1, g_c1, be_c1,
                                                   b_c2, g_c2, be_c2, ws);
  k_fuse1<<<dim3(3125), dim3(256), 0, stream>>>(w_f1, b_f1, g_g2, be_g2, ws);
  k_fuse2<<<dim3(3125), dim3(256), 0, stream>>>(w_f2, b_f2, g_f1, be_f1, ws);
  k_final<<<dim3(6250), dim3(256), 0, stream>>>(g_f2, be_f2, ws, out);
}

// Round 3
// 1614.266 us; speedup vs baseline: 3.1970x; 1.5491x over previous
//
#include <hip/hip_runtime.h>
#include <hip/hip_bf16.h>
#include <cmath>

#define E_EDGES 800000
#define N_NODES 50000
#define BN_EPS 1e-5f

typedef __attribute__((ext_vector_type(8))) short short8;
typedef __attribute__((ext_vector_type(4))) float float4v;
typedef unsigned short ushort_t;

// ---- workspace layout (float offsets) ----
#define OFF_S1SUM 0
#define OFF_S1SQ 128
#define OFF_S2SUM 256
#define OFF_S2SQ 512
#define OFF_GS1SUM 768
#define OFF_GS1SQ 832
#define OFF_GS2SUM 896
#define OFF_GS2SQ 960
#define OFF_FS1SUM 1024
#define OFF_FS1SQ 1152
#define OFF_FS2SUM 1280
#define OFF_FS2SQ 1408
#define OFF_NODE 1536                          // node_acc [N,128]
#define OFF_TG2 (OFF_NODE + N_NODES * 128)     // tg2 [N,64]
#define OFF_TF1 (OFF_TG2 + N_NODES * 64)       // tf1 [N,128]
#define OFF_TF2 OFF_NODE                       // tf2 reuses node_acc (dead after fuse1)
#define OFF_W1T (OFF_TF1 + N_NODES * 128)      // w1T bf16 [128][64]  (4096 floats)
#define OFF_W2T (OFF_W1T + 4096)               // w2T bf16 [256][128] (16384 floats)

__device__ __forceinline__ float frcp_(float x) { return __builtin_amdgcn_rcpf(x); }
__device__ __forceinline__ float sigmoid_(float x) { return frcp_(1.0f + __expf(-x)); }
__device__ __forceinline__ float softplus_(float x) {
  return (x > 20.0f) ? x : __logf(1.0f + __expf(x));
}
__device__ __forceinline__ float silu_(float x) { return x * frcp_(1.0f + __expf(-x)); }

__device__ __forceinline__ ushort_t f2bf(float f) {
  __hip_bfloat16 h = __float2bfloat16(f);
  return *(ushort_t*)&h;
}

// ---------------- prep: transpose+convert weights to bf16 in ws ----------------
__global__ __launch_bounds__(256) void k_prep(const float* __restrict__ w1,
                                              const float* __restrict__ w2,
                                              float* __restrict__ ws) {
  ushort_t* w1t = (ushort_t*)(ws + OFF_W1T);
  ushort_t* w2t = (ushort_t*)(ws + OFF_W2T);
  int idx = blockIdx.x * 256 + threadIdx.x;
  if (idx < 128 * 64) {  // w1T[c][k], K padded 34 -> 64 with zeros
    int c = idx >> 6, k = idx & 63;
    float v = (k < 34) ? w1[k * 128 + c] : 0.0f;
    w1t[idx] = f2bf(v);
  }
  int j = idx - 128 * 64;
  if (j >= 0 && j < 256 * 128) {  // w2T[c][k]
    int c = j >> 7, k = j & 127;
    w2t[j] = f2bf(w2[k * 256 + c]);
  }
}

// ---------------- chem branch: 64-edge tile, 4 waves; wave owns ALL 64 edges x 32-col slice ----
// MODE 1: t1 batch stats.  MODE 2: t2 batch stats.  MODE 3: gate + scatter.
// MFMA 16x16x32 bf16. A-frag: A[m=lane&15][k=quad*8+j]. B-frag: B[k=quad*8+j][n=lane&15].
// C/D: col=lane&15, row=quad*4+reg.
template <int MODE>
__global__ __launch_bounds__(256) void k_chem(
    const float* __restrict__ chem, const int* __restrict__ vids,
    const float* __restrict__ b1, const float* __restrict__ g1, const float* __restrict__ be1,
    const float* __restrict__ b2, const float* __restrict__ g2, const float* __restrict__ be2,
    float* __restrict__ ws) {
  __shared__ ushort_t xB[64 * 72];   // x tile bf16, K padded to 64 (zeros), row stride 72
  __shared__ ushort_t hS[64 * 136];  // h tile bf16, row stride 136
  __shared__ float A1[128], C1[128];
  __shared__ float sh2[512];         // MODE2: col sums/sq of t2; MODE3: A2[0:256], C2[256:512]
  __shared__ float sSum[128], sSq[128];  // MODE1 t1 stats
  __shared__ int vidS[64];

  const int t = threadIdx.x;
  const int e_base = blockIdx.x * 64;
  const int wv = t >> 6, ln = t & 63, r15 = ln & 15, qd = ln >> 4;
  const float invE = 1.0f / (float)E_EDGES;
  const ushort_t* w1t = (const ushort_t*)(ws + OFF_W1T);
  const ushort_t* w2t = (const ushort_t*)(ws + OFF_W2T);

  // ---- phase 1: BN affines / zero stats ----
  if (MODE == 1) {
    if (t < 128) { sSum[t] = 0.0f; sSq[t] = 0.0f; }
  } else {
    if (t < 128) {  // fold BN1: bn1(t1) = A1*acc + C1  (t1 = acc + b1)
      float s = ws[OFF_S1SUM + t], q = ws[OFF_S1SQ + t];
      float m = s * invE, v = q * invE - m * m;
      float a = g1[t] * rsqrtf(v + BN_EPS);
      A1[t] = a;
      C1[t] = a * (b1[t] - m) + be1[t];
    }
    if (MODE == 2) {
      sh2[t] = 0.0f; sh2[256 + t] = 0.0f;
    } else {  // MODE 3: fold BN2
      float s = ws[OFF_S2SUM + t], q = ws[OFF_S2SQ + t];
      float m = s * invE, v = q * invE - m * m;
      float a = g2[t] * rsqrtf(v + BN_EPS);
      sh2[t] = a;
      sh2[256 + t] = a * (b2[t] - m) + be2[t];
      if (t < 64) vidS[t] = vids[e_base + t];
    }
  }

  // ---- phase 2: fill xB (k>=34 zero-padded; no division) ----
  for (int i = t; i < 64 * 64; i += 256) {
    int e = i >> 6, k = i & 63;
    xB[e * 72 + k] = (k < 34) ? f2bf(chem[(e_base + e) * 34 + k]) : (ushort_t)0;
  }
  __syncthreads();

  // ---- stage A: t1[64x128]; wave wv owns cols [32wv,32wv+32), all 64 edges ----
  short8 xa[4][2];
#pragma unroll
  for (int rb = 0; rb < 4; ++rb)
#pragma unroll
    for (int ks = 0; ks < 2; ++ks)
      xa[rb][ks] = *(const short8*)&xB[(16 * rb + r15) * 72 + ks * 32 + 8 * qd];

#pragma unroll
  for (int cf = 0; cf < 2; ++cf) {
    const int col = 32 * wv + 16 * cf + r15;
    short8 wb0 = *(const short8*)&w1t[col * 64 + 8 * qd];
    short8 wb1 = *(const short8*)&w1t[col * 64 + 32 + 8 * qd];
    float4v acc[4];
#pragma unroll
    for (int rb = 0; rb < 4; ++rb) {
      acc[rb] = (float4v){0.0f, 0.0f, 0.0f, 0.0f};
      acc[rb] = __builtin_amdgcn_mfma_f32_16x16x32_bf16(xa[rb][0], wb0, acc[rb], 0, 0, 0);
      acc[rb] = __builtin_amdgcn_mfma_f32_16x16x32_bf16(xa[rb][1], wb1, acc[rb], 0, 0, 0);
    }
    if (MODE == 1) {
      float b = b1[col];
      float s = 0.0f, q = 0.0f;
#pragma unroll
      for (int rb = 0; rb < 4; ++rb)
#pragma unroll
        for (int r = 0; r < 4; ++r) {
          float v = acc[rb][r] + b;
          s += v; q += v * v;
        }
      s += __shfl_xor(s, 16); q += __shfl_xor(q, 16);
      s += __shfl_xor(s, 32); q += __shfl_xor(q, 32);
      if (ln < 16) { atomicAdd(&sSum[col], s); atomicAdd(&sSq[col], q); }
    } else {
      float a1c = A1[col], c1c = C1[col];
#pragma unroll
      for (int rb = 0; rb < 4; ++rb)
#pragma unroll
        for (int r = 0; r < 4; ++r) {
          float hv = silu_(fmaf(a1c, acc[rb][r], c1c));
          hS[(16 * rb + 4 * qd + r) * 136 + col] = f2bf(hv);
        }
    }
  }

  if (MODE == 1) {
    __syncthreads();
    if (t < 128) {
      atomicAdd(ws + OFF_S1SUM + t, sSum[t]);
      atomicAdd(ws + OFF_S1SQ + t, sSq[t]);
    }
    return;
  }
  __syncthreads();  // hS complete (waves write cols owned by others' read range)

  // ---- stage B: t2[64x256]; wave owns filter cols [32wv,+32) and core cols [128+32wv,+32) ----
  short8 ha[4][4];
#pragma unroll
  for (int rb = 0; rb < 4; ++rb)
#pragma unroll
    for (int ks = 0; ks < 4; ++ks)
      ha[rb][ks] = *(const short8*)&hS[(16 * rb + r15) * 136 + ks * 32 + 8 * qd];

#pragma unroll
  for (int cf = 0; cf < 2; ++cf) {
    const int colF = 32 * wv + 16 * cf + r15;
    float4v aF[4], aC[4];
#pragma unroll
    for (int rb = 0; rb < 4; ++rb) {
      aF[rb] = (float4v){0.0f, 0.0f, 0.0f, 0.0f};
      aC[rb] = (float4v){0.0f, 0.0f, 0.0f, 0.0f};
    }
#pragma unroll
    for (int ks = 0; ks < 4; ++ks) {
      short8 bF = *(const short8*)&w2t[colF * 128 + ks * 32 + 8 * qd];
      short8 bC = *(const short8*)&w2t[(128 + colF) * 128 + ks * 32 + 8 * qd];
#pragma unroll
      for (int rb = 0; rb < 4; ++rb) {
        aF[rb] = __builtin_amdgcn_mfma_f32_16x16x32_bf16(ha[rb][ks], bF, aF[rb], 0, 0, 0);
        aC[rb] = __builtin_amdgcn_mfma_f32_16x16x32_bf16(ha[rb][ks], bC, aC[rb], 0, 0, 0);
      }
    }
    if (MODE == 2) {
      float bFb = b2[colF], bCb = b2[128 + colF];
      float sF = 0, qF = 0, sC = 0, qC = 0;
#pragma unroll
      for (int rb = 0; rb < 4; ++rb)
#pragma unroll
        for (int r = 0; r < 4; ++r) {
          float vF = aF[rb][r] + bFb, vC = aC[rb][r] + bCb;
          sF += vF; qF += vF * vF; sC += vC; qC += vC * vC;
        }
      sF += __shfl_xor(sF, 16); qF += __shfl_xor(qF, 16);
      sF += __shfl_xor(sF, 32); qF += __shfl_xor(qF, 32);
      sC += __shfl_xor(sC, 16); qC += __shfl_xor(qC, 16);
      sC += __shfl_xor(sC, 32); qC += __shfl_xor(qC, 32);
      if (ln < 16) {
        atomicAdd(&sh2[colF], sF); atomicAdd(&sh2[256 + colF], qF);
        atomicAdd(&sh2[128 + colF], sC); atomicAdd(&sh2[384 + colF], qC);
      }
    } else {  // MODE 3: BN2 + gate + scatter (16-lane group: 16 consecutive cols of ONE vid)
      float aF2 = sh2[colF], cF2 = sh2[256 + colF];
      float aC2 = sh2[128 + colF], cC2 = sh2[384 + colF];
#pragma unroll
      for (int rb = 0; rb < 4; ++rb)
#pragma unroll
        for (int r = 0; r < 4; ++r) {
          float F = fmaf(aF2, aF[rb][r], cF2);
          float Co = fmaf(aC2, aC[rb][r], cC2);
          float g = sigmoid_(F) * softplus_(Co);
          int e = 16 * rb + 4 * qd + r;
          atomicAdd(ws + OFF_NODE + (size_t)vidS[e] * 128 + colF, g);
        }
    }
  }

  if (MODE == 2) {
    __syncthreads();
    if (t < 256) {
      atomicAdd(ws + OFF_S2SUM + t, sh2[t]);
      atomicAdd(ws + OFF_S2SQ + t, sh2[256 + t]);
    }
  }
}

// ---------------- geom / fuse: wave-per-4-node kernels (k-outer loops: weights loaded once) ----
__global__ __launch_bounds__(256) void k_geom_stats1(const float* __restrict__ geom,
                                                     const float* __restrict__ wg1,
                                                     const float* __restrict__ bg1,
                                                     float* __restrict__ ws) {
  __shared__ float ssum[64], ssq[64];
  const int t = threadIdx.x, lane = t & 63, w = t >> 6;
  if (t < 64) { ssum[t] = 0.0f; ssq[t] = 0.0f; }
  __syncthreads();
  const float bcol = bg1[lane];
  const int nb = blockIdx.x * 16 + w * 4;
  float x[4], acc[4];
#pragma unroll
  for (int u = 0; u < 4; u++) {
    x[u] = (lane < 48) ? geom[(nb + u) * 48 + lane] : 0.0f;
    acc[u] = bcol;
  }
#pragma unroll 16
  for (int k = 0; k < 48; k++) {
    float wvv = wg1[k * 64 + lane];
#pragma unroll
    for (int u = 0; u < 4; u++) acc[u] = fmaf(__shfl(x[u], k), wvv, acc[u]);
  }
  float bs = 0.0f, bq = 0.0f;
#pragma unroll
  for (int u = 0; u < 4; u++) { bs += acc[u]; bq += acc[u] * acc[u]; }
  atomicAdd(&ssum[lane], bs);
  atomicAdd(&ssq[lane], bq);
  __syncthreads();
  if (t < 64) {
    atomicAdd(ws + OFF_GS1SUM + t, ssum[t]);
    atomicAdd(ws + OFF_GS1SQ + t, ssq[t]);
  }
}

__global__ __launch_bounds__(256) void k_geom_main(
    const float* __restrict__ geom, const float* __restrict__ wg1,
    const float* __restrict__ bg1, const float* __restrict__ gg1,
    const float* __restrict__ beg1, const float* __restrict__ wg2,
    const float* __restrict__ bg2, float* __restrict__ ws) {
  __shared__ float ssum[64], ssq[64];
  const int t = threadIdx.x, lane = t & 63, w = t >> 6;
  if (t < 64) { ssum[t] = 0.0f; ssq[t] = 0.0f; }
  const float invN = 1.0f / (float)N_NODES;
  float s1 = ws[OFF_GS1SUM + lane], q1 = ws[OFF_GS1SQ + lane];
  float m1 = s1 * invN, v1 = q1 * invN - m1 * m1;
  float a1 = gg1[lane] * rsqrtf(v1 + BN_EPS);
  float c1 = beg1[lane] - a1 * m1;
  const float bcol = bg1[lane], b2col = bg2[lane];
  __syncthreads();
  const int nb = blockIdx.x * 16 + w * 4;
  float x[4], tg1[4], hg[4], acc[4];
#pragma unroll
  for (int u = 0; u < 4; u++) {
    x[u] = (lane < 48) ? geom[(nb + u) * 48 + lane] : 0.0f;
    tg1[u] = bcol;
  }
#pragma unroll 16
  for (int k = 0; k < 48; k++) {
    float wvv = wg1[k * 64 + lane];
#pragma unroll
    for (int u = 0; u < 4; u++) tg1[u] = fmaf(__shfl(x[u], k), wvv, tg1[u]);
  }
#pragma unroll
  for (int u = 0; u < 4; u++) {
    hg[u] = silu_(fmaf(a1, tg1[u], c1));
    acc[u] = b2col;
  }
#pragma unroll 16
  for (int k = 0; k < 64; k++) {
    float wvv = wg2[k * 64 + lane];
#pragma unroll
    for (int u = 0; u < 4; u++) acc[u] = fmaf(__shfl(hg[u], k), wvv, acc[u]);
  }
  float bs = 0.0f, bq = 0.0f;
#pragma unroll
  for (int u = 0; u < 4; u++) {
    ws[OFF_TG2 + (nb + u) * 64 + lane] = acc[u];  // raw tg2; BN applied in fuse1
    bs += acc[u]; bq += acc[u] * acc[u];
  }
  atomicAdd(&ssum[lane], bs);
  atomicAdd(&ssq[lane], bq);
  __syncthreads();
  if (t < 64) {
    atomicAdd(ws + OFF_GS2SUM + t, ssum[t]);
    atomicAdd(ws + OFF_GS2SQ + t, ssq[t]);
  }
}

__global__ __launch_bounds__(256) void k_fuse1(const float* __restrict__ wf1,
                                               const float* __restrict__ bf1,
                                               const float* __restrict__ gg2,
                                               const float* __restrict__ beg2,
                                               float* __restrict__ ws) {
  __shared__ float ssum[128], ssq[128];
  const int t = threadIdx.x, lane = t & 63, w = t >> 6;
  if (t < 128) { ssum[t] = 0.0f; ssq[t] = 0.0f; }
  const float invN = 1.0f / (float)N_NODES;
  float s2 = ws[OFF_GS2SUM + lane], q2 = ws[OFF_GS2SQ + lane];
  float mg = s2 * invN, vg = q2 * invN - mg * mg;
  float ag = gg2[lane] * rsqrtf(vg + BN_EPS);
  float cg_ = beg2[lane] - ag * mg;
  const float bA = bf1[lane], bB = bf1[64 + lane];
  __syncthreads();
  const int nb = blockIdx.x * 16 + w * 4;
  float xa[4], xb[4], xg[4], acc1[4], acc2[4];
#pragma unroll
  for (int u = 0; u < 4; u++) {
    int n = nb + u;
    xa[u] = ws[OFF_NODE + n * 128 + lane];
    xb[u] = ws[OFF_NODE + n * 128 + 64 + lane];
    xg[u] = fmaf(ag, ws[OFF_TG2 + n * 64 + lane], cg_);
    acc1[u] = bA; acc2[u] = bB;
  }
#pragma unroll 16
  for (int k = 0; k < 64; k++) {
    float w1v = wf1[k * 128 + lane], w2v = wf1[k * 128 + 64 + lane];
#pragma unroll
    for (int u = 0; u < 4; u++) {
      float xk = __shfl(xa[u], k);
      acc1[u] = fmaf(xk, w1v, acc1[u]);
      acc2[u] = fmaf(xk, w2v, acc2[u]);
    }
  }
#pragma unroll 16
  for (int k = 0; k < 64; k++) {
    float w1v = wf1[(64 + k) * 128 + lane], w2v = wf1[(64 + k) * 128 + 64 + lane];
#pragma unroll
    for (int u = 0; u < 4; u++) {
      float xk = __shfl(xb[u], k);
      acc1[u] = fmaf(xk, w1v, acc1[u]);
      acc2[u] = fmaf(xk, w2v, acc2[u]);
    }
  }
#pragma unroll 16
  for (int k = 0; k < 64; k++) {
    float w1v = wf1[(128 + k) * 128 + lane], w2v = wf1[(128 + k) * 128 + 64 + lane];
#pragma unroll
    for (int u = 0; u < 4; u++) {
      float xk = __shfl(xg[u], k);
      acc1[u] = fmaf(xk, w1v, acc1[u]);
      acc2[u] = fmaf(xk, w2v, acc2[u]);
    }
  }
  float sA = 0, qA = 0, sB = 0, qB = 0;
#pragma unroll
  for (int u = 0; u < 4; u++) {
    int n = nb + u;
    ws[OFF_TF1 + n * 128 + lane] = acc1[u];
    ws[OFF_TF1 + n * 128 + 64 + lane] = acc2[u];
    sA += acc1[u]; qA += acc1[u] * acc1[u];
    sB += acc2[u]; qB += acc2[u] * acc2[u];
  }
  atomicAdd(&ssum[lane], sA); atomicAdd(&ssq[lane], qA);
  atomicAdd(&ssum[64 + lane], sB); atomicAdd(&ssq[64 + lane], qB);
  __syncthreads();
  if (t < 128) {
    atomicAdd(ws + OFF_FS1SUM + t, ssum[t]);
    atomicAdd(ws + OFF_FS1SQ + t, ssq[t]);
  }
}

__global__ __launch_bounds__(256) void k_fuse2(const float* __restrict__ wf2,
                                               const float* __restrict__ bf2,
                                               const float* __restrict__ gf1,
                                               const float* __restrict__ bef1,
                                               float* __restrict__ ws) {
  __shared__ float ssum[128], ssq[128];
  const int t = threadIdx.x, lane = t & 63, w = t >> 6;
  if (t < 128) { ssum[t] = 0.0f; ssq[t] = 0.0f; }
  const float invN = 1.0f / (float)N_NODES;
  float sA_ = ws[OFF_FS1SUM + lane], qA_ = ws[OFF_FS1SQ + lane];
  float mA = sA_ * invN, vA = qA_ * invN - mA * mA;
  float aA = gf1[lane] * rsqrtf(vA + BN_EPS);
  float cA = bef1[lane] - aA * mA;
  float sB_ = ws[OFF_FS1SUM + 64 + lane], qB_ = ws[OFF_FS1SQ + 64 + lane];
  float mB = sB_ * invN, vB = qB_ * invN - mB * mB;
  float aB = gf1[64 + lane] * rsqrtf(vB + BN_EPS);
  float cB = bef1[64 + lane] - aB * mB;
  const float b1c = bf2[lane], b2c = bf2[64 + lane];
  __syncthreads();
  const int nb = blockIdx.x * 16 + w * 4;
  float ha[4], hb[4], acc1[4], acc2[4];
#pragma unroll
  for (int u = 0; u < 4; u++) {
    int n = nb + u;
    ha[u] = silu_(fmaf(aA, ws[OFF_TF1 + n * 128 + lane], cA));
    hb[u] = silu_(fmaf(aB, ws[OFF_TF1 + n * 128 + 64 + lane], cB));
    acc1[u] = b1c; acc2[u] = b2c;
  }
#pragma unroll 16
  for (int k = 0; k < 64; k++) {
    float w1v = wf2[k * 128 + lane], w2v = wf2[k * 128 + 64 + lane];
#pragma unroll
    for (int u = 0; u < 4; u++) {
      float xk = __shfl(ha[u], k);
      acc1[u] = fmaf(xk, w1v, acc1[u]);
      acc2[u] = fmaf(xk, w2v, acc2[u]);
    }
  }
#pragma unroll 16
  for (int k = 0; k < 64; k++) {
    float w1v = wf2[(64 + k) * 128 + lane], w2v = wf2[(64 + k) * 128 + 64 + lane];
#pragma unroll
    for (int u = 0; u < 4; u++) {
      float xk = __shfl(hb[u], k);
      acc1[u] = fmaf(xk, w1v, acc1[u]);
      acc2[u] = fmaf(xk, w2v, acc2[u]);
    }
  }
  float sA = 0, qA = 0, sB = 0, qB = 0;
#pragma unroll
  for (int u = 0; u < 4; u++) {
    int n = nb + u;
    ws[OFF_TF2 + n * 128 + lane] = acc1[u];   // overwrites node_acc (dead after fuse1)
    ws[OFF_TF2 + n * 128 + 64 + lane] = acc2[u];
    sA += acc1[u]; qA += acc1[u] * acc1[u];
    sB += acc2[u]; qB += acc2[u] * acc2[u];
  }
  atomicAdd(&ssum[lane], sA); atomicAdd(&ssq[lane], qA);
  atomicAdd(&ssum[64 + lane], sB); atomicAdd(&ssq[64 + lane], qB);
  __syncthreads();
  if (t < 128) {
    atomicAdd(ws + OFF_FS2SUM + t, ssum[t]);
    atomicAdd(ws + OFF_FS2SQ + t, ssq[t]);
  }
}

__global__ __launch_bounds__(256) void k_final(const float* __restrict__ gf2,
                                               const float* __restrict__ bef2,
                                               const float* __restrict__ ws,
                                               float* __restrict__ out) {
  const int idx = blockIdx.x * 256 + threadIdx.x;
  const int base = idx * 4;
  if (base >= N_NODES * 128) return;
  const float invN = 1.0f / (float)N_NODES;
  const int c0 = base & 127;
  float4 v = *(const float4*)(ws + OFF_TF2 + base);
  float vv[4] = {v.x, v.y, v.z, v.w}, r[4];
#pragma unroll
  for (int j = 0; j < 4; j++) {
    int c = c0 + j;
    float s = ws[OFF_FS2SUM + c], q = ws[OFF_FS2SQ + c];
    float m = s * invN, var = q * invN - m * m;
    float a = gf2[c] * rsqrtf(var + BN_EPS);
    r[j] = fmaf(a, vv[j] - m, bef2[c]);
  }
  *(float4*)(out + base) = make_float4(r[0], r[1], r[2], r[3]);
}

extern "C" void kernel_launch(void* const* d_in, const int* in_sizes, int n_in,
                              void* d_out, int out_size, void* d_ws, size_t ws_size,
                              hipStream_t stream) {
  const float* chem = (const float*)d_in[0];
  const float* geom = (const float*)d_in[1];
  const int* vids = (const int*)d_in[2];
  const float* w_c1 = (const float*)d_in[3];  const float* b_c1 = (const float*)d_in[4];
  const float* g_c1 = (const float*)d_in[5];  const float* be_c1 = (const float*)d_in[6];
  const float* w_c2 = (const float*)d_in[7];  const float* b_c2 = (const float*)d_in[8];
  const float* g_c2 = (const float*)d_in[9];  const float* be_c2 = (const float*)d_in[10];
  const float* w_g1 = (const float*)d_in[11]; const float* b_g1 = (const float*)d_in[12];
  const float* g_g1 = (const float*)d_in[13]; const float* be_g1 = (const float*)d_in[14];
  const float* w_g2 = (const float*)d_in[15]; const float* b_g2 = (const float*)d_in[16];
  const float* g_g2 = (const float*)d_in[17]; const float* be_g2 = (const float*)d_in[18];
  const float* w_f1 = (const float*)d_in[19]; const float* b_f1 = (const float*)d_in[20];
  const float* g_f1 = (const float*)d_in[21]; const float* be_f1 = (const float*)d_in[22];
  const float* w_f2 = (const float*)d_in[23]; const float* b_f2 = (const float*)d_in[24];
  const float* g_f2 = (const float*)d_in[25]; const float* be_f2 = (const float*)d_in[26];
  float* ws = (float*)d_ws;
  float* out = (float*)d_out;

  // zero stats + node accumulator (ws is poisoned 0xAA before every launch)
  hipMemsetAsync(d_ws, 0, (size_t)(OFF_NODE + N_NODES * 128) * sizeof(float), stream);

  k_prep<<<dim3(160), dim3(256), 0, stream>>>(w_c1, w_c2, ws);
  k_chem<1><<<dim3(12500), dim3(256), 0, stream>>>(chem, vids, b_c1, g_c1, be_c1,
                                                   b_c2, g_c2, be_c2, ws);
  k_chem<2><<<dim3(12500), dim3(256), 0, stream>>>(chem, vids, b_c1, g_c1, be_c1,
                                                   b_c2, g_c2, be_c2, ws);
  k_geom_stats1<<<dim3(3125), dim3(256), 0, stream>>>(geom, w_g1, b_g1, ws);
  k_geom_main<<<dim3(3125), dim3(256), 0, stream>>>(geom, w_g1, b_g1, g_g1, be_g1, w_g2, b_g2, ws);
  k_chem<3><<<dim3(12500), dim3(256), 0, stream>>>(chem, vids, b_c1, g_c1, be_c1,
                                                   b_c2, g_c2, be_c2, ws);
  k_fuse1<<<dim3(3125), dim3(256), 0, stream>>>(w_f1, b_f1, g_g2, be_g2, ws);
  k_fuse2<<<dim3(3125), dim3(256), 0, stream>>>(w_f2, b_f2, g_f1, be_f1, ws);
  k_final<<<dim3(6250), dim3(256), 0, stream>>>(g_f2, be_f2, ws, out);
}

// Round 4
// 1189.509 us; speedup vs baseline: 4.3386x; 1.3571x over previous
//
#include <hip/hip_runtime.h>
#include <hip/hip_bf16.h>
#include <cmath>

#define E_EDGES 800000
#define N_NODES 50000
#define BN_EPS 1e-5f

typedef __attribute__((ext_vector_type(8))) short short8;
typedef __attribute__((ext_vector_type(4))) float float4v;
typedef unsigned short ushort_t;

#define MFMA16(a, b, c) __builtin_amdgcn_mfma_f32_16x16x32_bf16((a), (b), (c), 0, 0, 0)

// ---- workspace layout (float offsets) ----
#define OFF_GX 0                               // Gram(x) [48][48] (rows 34=ones)
#define OFF_GH 2304                            // Gram(h) [144][144] (row 128=ones)
#define OFF_A1 23040
#define OFF_C1 23168
#define OFF_A2 23296
#define OFF_C2 23552
#define OFF_GS1SUM 23808
#define OFF_GS1SQ 23872
#define OFF_GS2SUM 23936
#define OFF_GS2SQ 24000
#define OFF_FS1SUM 24064
#define OFF_FS1SQ 24192
#define OFF_FS2SUM 24320
#define OFF_FS2SQ 24448
#define OFF_NODE 24576                         // node_acc [N,128]
#define OFF_TG2 (OFF_NODE + N_NODES * 128)     // tg2 [N,64]
#define OFF_TF1 (OFF_TG2 + N_NODES * 64)       // tf1 [N,128]
#define OFF_TF2 OFF_NODE                       // tf2 reuses node_acc
#define OFF_W1T (OFF_TF1 + N_NODES * 128)      // w1T bf16 [128][64]
#define OFF_W2T (OFF_W1T + 4096)               // w2T bf16 [256][128]

__device__ __forceinline__ float frcp_(float x) { return __builtin_amdgcn_rcpf(x); }
__device__ __forceinline__ float sigmoid_(float x) { return frcp_(1.0f + __expf(-x)); }
__device__ __forceinline__ float softplus_(float x) {
  return (x > 20.0f) ? x : __logf(1.0f + __expf(x));
}
__device__ __forceinline__ float silu_(float x) { return x * frcp_(1.0f + __expf(-x)); }

__device__ __forceinline__ ushort_t f2bf(float f) {
  __hip_bfloat16 h = __float2bfloat16(f);
  return *(ushort_t*)&h;
}
__device__ __forceinline__ float bf2f(ushort_t u) {
  return __uint_as_float(((unsigned)u) << 16);
}

// x A-frag for MFMA 16x16x32: lane holds x[e][8qd..8qd+7] (ks=0) and x[e][32..33] pad (ks=1)
__device__ __forceinline__ void load_xfrag(const float* __restrict__ chem, int e, int qd,
                                           short8* x0, short8* x1) {
  const float* xe = chem + e * 34;
  float2 p0 = *(const float2*)(xe + 8 * qd);
  float2 p1 = *(const float2*)(xe + 8 * qd + 2);
  float2 p2 = *(const float2*)(xe + 8 * qd + 4);
  float2 p3 = *(const float2*)(xe + 8 * qd + 6);
  short8 a;
  a[0] = (short)f2bf(p0.x); a[1] = (short)f2bf(p0.y);
  a[2] = (short)f2bf(p1.x); a[3] = (short)f2bf(p1.y);
  a[4] = (short)f2bf(p2.x); a[5] = (short)f2bf(p2.y);
  a[6] = (short)f2bf(p3.x); a[7] = (short)f2bf(p3.y);
  *x0 = a;
  short8 b = (short8){0, 0, 0, 0, 0, 0, 0, 0};
  if (qd == 0) {
    float2 pt = *(const float2*)(xe + 32);
    b[0] = (short)f2bf(pt.x); b[1] = (short)f2bf(pt.y);
  }
  *x1 = b;
}

// ---------------- prep: transpose+convert weights to bf16 in ws ----------------
__global__ __launch_bounds__(256) void k_prep(const float* __restrict__ w1,
                                              const float* __restrict__ w2,
                                              float* __restrict__ ws) {
  ushort_t* w1t = (ushort_t*)(ws + OFF_W1T);
  ushort_t* w2t = (ushort_t*)(ws + OFF_W2T);
  int idx = blockIdx.x * 256 + threadIdx.x;
  if (idx < 128 * 64) {  // w1T[c][k], K padded 34 -> 64 with zeros
    int c = idx >> 6, k = idx & 63;
    float v = (k < 34) ? w1[k * 128 + c] : 0.0f;
    w1t[idx] = f2bf(v);
  }
  int j = idx - 128 * 64;
  if (j >= 0 && j < 256 * 128) {  // w2T[c][k]
    int c = j >> 7, k = j & 127;
    w2t[j] = f2bf(w2[k * 256 + c]);
  }
}

// ---------------- k_xstats: Gram(x) 48x48 (row 34 = ones -> col sums) ----------------
__global__ __launch_bounds__(256) void k_xstats(const float* __restrict__ chem,
                                                float* __restrict__ ws) {
  __shared__ __align__(16) ushort_t xT[2][48 * 72];  // [feat][edge], row stride 72
  const int t = threadIdx.x, wv = t >> 6, ln = t & 63, r15 = ln & 15, qd = ln >> 4;
  // static rows 34..47 (34=ones for e<64, rest zero), both buffers
  for (int i = t; i < 2 * 14 * 72; i += 256) {
    int b = i / (14 * 72), j = i % (14 * 72);
    int rr = j / 72, e = j % 72;
    xT[b][(34 + rr) * 72 + e] = (rr == 0 && e < 64) ? f2bf(1.0f) : (ushort_t)0;
  }
  float4v g0 = {0, 0, 0, 0}, g1 = {0, 0, 0, 0};
#pragma unroll 2
  for (int it = 0; it < 10; ++it) {
    const int st = blockIdx.x * 10 + it;
    const int buf = it & 1;
    for (int i = t; i < 64 * 34; i += 256) {  // coalesced linear read, transposed store
      int e = i / 34, k = i - e * 34;
      xT[buf][k * 72 + e] = f2bf(chem[st * 2176 + i]);
    }
    __syncthreads();
    const ushort_t* xb = &xT[buf][0];
#pragma unroll
    for (int ks = 0; ks < 2; ++ks) {
      const ushort_t* xk = xb + ks * 32 + 8 * qd;
      short8 f0 = *(const short8*)&xk[(0 + r15) * 72];
      short8 f1 = *(const short8*)&xk[(16 + r15) * 72];
      short8 f2v = *(const short8*)&xk[(32 + r15) * 72];
      if (wv == 0) { g0 = MFMA16(f0, f0, g0); g1 = MFMA16(f0, f1, g1); }
      else if (wv == 1) { g0 = MFMA16(f0, f2v, g0); g1 = MFMA16(f1, f1, g1); }
      else if (wv == 2) { g0 = MFMA16(f1, f2v, g0); }
      else { g0 = MFMA16(f2v, f2v, g0); }
    }
  }
  float* GX = ws + OFF_GX;
  // flush: D row = 16ti+4qd+r, col = 16tj+r15
  int ti0, tj0, ti1 = -1, tj1 = -1;
  if (wv == 0) { ti0 = 0; tj0 = 0; ti1 = 0; tj1 = 1; }
  else if (wv == 1) { ti0 = 0; tj0 = 2; ti1 = 1; tj1 = 1; }
  else if (wv == 2) { ti0 = 1; tj0 = 2; }
  else { ti0 = 2; tj0 = 2; }
#pragma unroll
  for (int r = 0; r < 4; ++r)
    atomicAdd(&GX[(16 * ti0 + 4 * qd + r) * 48 + 16 * tj0 + r15], g0[r]);
  if (ti1 >= 0)
#pragma unroll
    for (int r = 0; r < 4; ++r)
      atomicAdd(&GX[(16 * ti1 + 4 * qd + r) * 48 + 16 * tj1 + r15], g1[r]);
}

// ---------------- k_bn1: BN1 affine from Gram(x) ----------------
__global__ __launch_bounds__(64) void k_bn1(const float* __restrict__ b1,
                                            const float* __restrict__ g1,
                                            const float* __restrict__ be1,
                                            float* __restrict__ ws) {
  const int c = blockIdx.x, i = threadIdx.x;
  __shared__ float wc[34];
  const ushort_t* w1t = (const ushort_t*)(ws + OFF_W1T);
  const float* GX = ws + OFF_GX;
  if (i < 34) wc[i] = bf2f(w1t[c * 64 + i]);
  __syncthreads();
  float p = 0.0f, ps = 0.0f;
  if (i < 34) {
    float gi = 0.0f;
    for (int j = 0; j < 34; ++j) {
      int a = i, b = j;
      if ((a >> 4) > (b >> 4)) { int tt = a; a = b; b = tt; }
      gi += GX[a * 48 + b] * wc[j];
    }
    p = wc[i] * gi;
    ps = wc[i] * GX[i * 48 + 34];  // xsum_i (upper tile)
  }
#pragma unroll
  for (int off = 1; off < 64; off <<= 1) {
    p += __shfl_xor(p, off);
    ps += __shfl_xor(ps, off);
  }
  if (i == 0) {
    const float E = (float)E_EDGES;
    float bc = b1[c];
    float sum = ps + E * bc;
    float sq = p + 2.0f * bc * ps + E * bc * bc;
    float m = sum / E, v = sq / E - m * m;
    float a = g1[c] * rsqrtf(v + BN_EPS);
    ws[OFF_A1 + c] = a;
    ws[OFF_C1 + c] = a * (bc - m) + be1[c];
  }
}

// ---------------- Gram(h) helpers: wave wv owns tile-cols {wv, 7-wv}, rows 0..tj + row 8 (ones)
template <int TJA, int TJB>  // TJA < TJB
__device__ __forceinline__ void ghstep(const ushort_t* hk, int r15, float4v (&g)[11]) {
  short8 f[TJB + 1];
#pragma unroll
  for (int i = 0; i <= TJB; ++i) f[i] = *(const short8*)&hk[(16 * i + r15) * 72];
  short8 f8 = *(const short8*)&hk[(128 + r15) * 72];
  int s = 0;
#pragma unroll
  for (int ti = 0; ti <= TJA; ++ti) { g[s] = MFMA16(f[ti], f[TJA], g[s]); ++s; }
  g[s] = MFMA16(f8, f[TJA], g[s]); ++s;
#pragma unroll
  for (int ti = 0; ti <= TJB; ++ti) { g[s] = MFMA16(f[ti], f[TJB], g[s]); ++s; }
  g[s] = MFMA16(f8, f[TJB], g[s]);
}

__device__ __forceinline__ void ghtile(float* GH, int ti, int tj, int r15, int qd,
                                       const float4v v) {
#pragma unroll
  for (int r = 0; r < 4; ++r)
    atomicAdd(&GH[(16 * ti + 4 * qd + r) * 144 + 16 * tj + r15], v[r]);
}

template <int TJA, int TJB>
__device__ __forceinline__ void ghflush(float* GH, int r15, int qd, const float4v (&g)[11]) {
  int s = 0;
#pragma unroll
  for (int ti = 0; ti <= TJA; ++ti) { ghtile(GH, ti, TJA, r15, qd, g[s]); ++s; }
  ghtile(GH, 8, TJA, r15, qd, g[s]); ++s;
#pragma unroll
  for (int ti = 0; ti <= TJB; ++ti) { ghtile(GH, ti, TJB, r15, qd, g[s]); ++s; }
  ghtile(GH, 8, TJB, r15, qd, g[s]);
}

// ---------------- k_h: stage A + Gram(h) ----------------
__global__ __launch_bounds__(256) void k_h(const float* __restrict__ chem,
                                           float* __restrict__ ws) {
  __shared__ __align__(16) ushort_t hT[2][144 * 72];  // [h-col][edge], row 128 = ones
  const int t = threadIdx.x, wv = t >> 6, ln = t & 63, r15 = ln & 15, qd = ln >> 4;
  const ushort_t* w1t = (const ushort_t*)(ws + OFF_W1T);
  for (int i = t; i < 2 * 16 * 72; i += 256) {  // rows 128..143 once, both buffers
    int b = i / (16 * 72), j = i % (16 * 72);
    int rr = j / 72, e = j % 72;
    hT[b][(128 + rr) * 72 + e] = (rr == 0 && e < 64) ? f2bf(1.0f) : (ushort_t)0;
  }
  float a1c[2], c1c[2];
#pragma unroll
  for (int cf = 0; cf < 2; ++cf) {
    int col = 32 * wv + 16 * cf + r15;
    a1c[cf] = ws[OFF_A1 + col];
    c1c[cf] = ws[OFF_C1 + col];
  }
  float4v gacc[11];
#pragma unroll
  for (int s = 0; s < 11; ++s) gacc[s] = (float4v){0, 0, 0, 0};

#pragma unroll 2
  for (int it = 0; it < 10; ++it) {
    const int st = blockIdx.x * 10 + it;
    const int buf = it & 1;
    const int e_base = st * 64;
    short8 xa0[4], xa1[4];
#pragma unroll
    for (int rb = 0; rb < 4; ++rb)
      load_xfrag(chem, e_base + 16 * rb + r15, qd, &xa0[rb], &xa1[rb]);
#pragma unroll
    for (int cf = 0; cf < 2; ++cf) {
      const int col = 32 * wv + 16 * cf + r15;
      short8 wb0 = *(const short8*)&w1t[col * 64 + 8 * qd];
      short8 wb1 = *(const short8*)&w1t[col * 64 + 32 + 8 * qd];
#pragma unroll
      for (int rb = 0; rb < 4; ++rb) {
        float4v acc = (float4v){0, 0, 0, 0};
        acc = MFMA16(xa0[rb], wb0, acc);
        acc = MFMA16(xa1[rb], wb1, acc);
        unsigned long long pk = 0;
#pragma unroll
        for (int r = 0; r < 4; ++r) {
          float hv = silu_(fmaf(a1c[cf], acc[r], c1c[cf]));
          pk |= ((unsigned long long)f2bf(hv)) << (16 * r);
        }
        *(unsigned long long*)&hT[buf][col * 72 + 16 * rb + 4 * qd] = pk;
      }
    }
    __syncthreads();
    const ushort_t* hb = &hT[buf][0];
#pragma unroll
    for (int ks = 0; ks < 2; ++ks) {
      const ushort_t* hk = hb + ks * 32 + 8 * qd;
      if (wv == 0) ghstep<0, 7>(hk, r15, gacc);
      else if (wv == 1) ghstep<1, 6>(hk, r15, gacc);
      else if (wv == 2) ghstep<2, 5>(hk, r15, gacc);
      else ghstep<3, 4>(hk, r15, gacc);
    }
  }
  float* GH = ws + OFF_GH;
  if (wv == 0) ghflush<0, 7>(GH, r15, qd, gacc);
  else if (wv == 1) ghflush<1, 6>(GH, r15, qd, gacc);
  else if (wv == 2) ghflush<2, 5>(GH, r15, qd, gacc);
  else ghflush<3, 4>(GH, r15, qd, gacc);
}

// ---------------- k_bn2: BN2 affine from Gram(h) ----------------
__global__ __launch_bounds__(128) void k_bn2(const float* __restrict__ b2,
                                             const float* __restrict__ g2,
                                             const float* __restrict__ be2,
                                             float* __restrict__ ws) {
  const int c = blockIdx.x, i = threadIdx.x;  // i < 128
  __shared__ float wcol[128];
  __shared__ float redQ[2], redS[2];
  const ushort_t* w2t = (const ushort_t*)(ws + OFF_W2T);
  const float* GH = ws + OFF_GH;
  wcol[i] = bf2f(w2t[c * 128 + i]);
  __syncthreads();
  float wi = wcol[i];
  float gi = 0.0f;
  for (int j = 0; j < 128; ++j) {
    int a = i, b = j;
    if ((a >> 4) > (b >> 4)) { int tt = a; a = b; b = tt; }
    gi += GH[a * 144 + b] * wcol[j];
  }
  float p = wi * gi;
  float ps = wi * GH[128 * 144 + i];  // hsum_i from ones row
#pragma unroll
  for (int off = 1; off < 64; off <<= 1) {
    p += __shfl_xor(p, off);
    ps += __shfl_xor(ps, off);
  }
  const int wv = i >> 6, ln = i & 63;
  if (ln == 0) { redQ[wv] = p; redS[wv] = ps; }
  __syncthreads();
  if (i == 0) {
    float q = redQ[0] + redQ[1], s = redS[0] + redS[1];
    const float E = (float)E_EDGES;
    float bc = b2[c];
    float sum = s + E * bc;
    float sq = q + 2.0f * bc * s + E * bc * bc;
    float m = sum / E, v = sq / E - m * m;
    float a = g2[c] * rsqrtf(v + BN_EPS);
    ws[OFF_A2 + c] = a;
    ws[OFF_C2 + c] = a * (bc - m) + be2[c];
  }
}

// ---------------- k_scatter: stage A + stage B + gate + scatter ----------------
__global__ __launch_bounds__(256) void k_scatter(const float* __restrict__ chem,
                                                 const int* __restrict__ vids,
                                                 float* __restrict__ ws) {
  __shared__ __align__(16) ushort_t hS[2][64 * 136];  // [edge][h-col]
  const int t = threadIdx.x, wv = t >> 6, ln = t & 63, r15 = ln & 15, qd = ln >> 4;
  const ushort_t* w1t = (const ushort_t*)(ws + OFF_W1T);
  const ushort_t* w2t = (const ushort_t*)(ws + OFF_W2T);
  float* node = ws + OFF_NODE;
  float a1c[2], c1c[2], aF2[2], cF2[2], aC2[2], cC2[2];
#pragma unroll
  for (int cf = 0; cf < 2; ++cf) {
    int col = 32 * wv + 16 * cf + r15;
    a1c[cf] = ws[OFF_A1 + col];
    c1c[cf] = ws[OFF_C1 + col];
    aF2[cf] = ws[OFF_A2 + col];
    cF2[cf] = ws[OFF_C2 + col];
    aC2[cf] = ws[OFF_A2 + 128 + col];
    cC2[cf] = ws[OFF_C2 + 128 + col];
  }
#pragma unroll 2
  for (int it = 0; it < 8; ++it) {
    const int st = blockIdx.x * 8 + it;
    if (st >= 12500) break;
    const int buf = it & 1;
    const int e_base = st * 64;
    const int myvid = vids[e_base + ln];
    // stage A: x direct from global -> MFMA -> BN1+SiLU -> hS (e-major)
    short8 xa0[4], xa1[4];
#pragma unroll
    for (int rb = 0; rb < 4; ++rb)
      load_xfrag(chem, e_base + 16 * rb + r15, qd, &xa0[rb], &xa1[rb]);
#pragma unroll
    for (int cf = 0; cf < 2; ++cf) {
      const int col = 32 * wv + 16 * cf + r15;
      short8 wb0 = *(const short8*)&w1t[col * 64 + 8 * qd];
      short8 wb1 = *(const short8*)&w1t[col * 64 + 32 + 8 * qd];
#pragma unroll
      for (int rb = 0; rb < 4; ++rb) {
        float4v acc = (float4v){0, 0, 0, 0};
        acc = MFMA16(xa0[rb], wb0, acc);
        acc = MFMA16(xa1[rb], wb1, acc);
#pragma unroll
        for (int r = 0; r < 4; ++r) {
          float hv = silu_(fmaf(a1c[cf], acc[r], c1c[cf]));
          hS[buf][(16 * rb + 4 * qd + r) * 136 + col] = f2bf(hv);
        }
      }
    }
    __syncthreads();
    // stage B: t2 cols [32wv,+32) (filter) and [128+32wv,+32) (core); gate; scatter
    const ushort_t* hb = &hS[buf][0];
#pragma unroll
    for (int cf = 0; cf < 2; ++cf) {
      const int colF = 32 * wv + 16 * cf + r15;
      float4v accF[4], accC[4];
#pragma unroll
      for (int rb = 0; rb < 4; ++rb) {
        accF[rb] = (float4v){0, 0, 0, 0};
        accC[rb] = (float4v){0, 0, 0, 0};
      }
#pragma unroll
      for (int ks = 0; ks < 4; ++ks) {
        short8 bF = *(const short8*)&w2t[colF * 128 + ks * 32 + 8 * qd];
        short8 bC = *(const short8*)&w2t[(128 + colF) * 128 + ks * 32 + 8 * qd];
#pragma unroll
        for (int rb = 0; rb < 4; ++rb) {
          short8 hf = *(const short8*)&hb[(16 * rb + r15) * 136 + ks * 32 + 8 * qd];
          accF[rb] = MFMA16(hf, bF, accF[rb]);
          accC[rb] = MFMA16(hf, bC, accC[rb]);
        }
      }
#pragma unroll
      for (int rb = 0; rb < 4; ++rb)
#pragma unroll
        for (int r = 0; r < 4; ++r) {
          float F = fmaf(aF2[cf], accF[rb][r], cF2[cf]);
          float Co = fmaf(aC2[cf], accC[rb][r], cC2[cf]);
          float gv = sigmoid_(F) * softplus_(Co);
          int vid = __shfl(myvid, 16 * rb + 4 * qd + r);
          atomicAdd(node + (size_t)vid * 128 + colF, gv);
        }
    }
  }
}

// ---------------- geom / fuse: wave-per-4-node kernels (unchanged structure) ----------------
__global__ __launch_bounds__(256) void k_geom_stats1(const float* __restrict__ geom,
                                                     const float* __restrict__ wg1,
                                                     const float* __restrict__ bg1,
                                                     float* __restrict__ ws) {
  __shared__ float ssum[64], ssq[64];
  const int t = threadIdx.x, lane = t & 63, w = t >> 6;
  if (t < 64) { ssum[t] = 0.0f; ssq[t] = 0.0f; }
  __syncthreads();
  const float bcol = bg1[lane];
  const int nb = blockIdx.x * 16 + w * 4;
  float x[4], acc[4];
#pragma unroll
  for (int u = 0; u < 4; u++) {
    x[u] = (lane < 48) ? geom[(nb + u) * 48 + lane] : 0.0f;
    acc[u] = bcol;
  }
#pragma unroll 16
  for (int k = 0; k < 48; k++) {
    float wvv = wg1[k * 64 + lane];
#pragma unroll
    for (int u = 0; u < 4; u++) acc[u] = fmaf(__shfl(x[u], k), wvv, acc[u]);
  }
  float bs = 0.0f, bq = 0.0f;
#pragma unroll
  for (int u = 0; u < 4; u++) { bs += acc[u]; bq += acc[u] * acc[u]; }
  atomicAdd(&ssum[lane], bs);
  atomicAdd(&ssq[lane], bq);
  __syncthreads();
  if (t < 64) {
    atomicAdd(ws + OFF_GS1SUM + t, ssum[t]);
    atomicAdd(ws + OFF_GS1SQ + t, ssq[t]);
  }
}

__global__ __launch_bounds__(256) void k_geom_main(
    const float* __restrict__ geom, const float* __restrict__ wg1,
    const float* __restrict__ bg1, const float* __restrict__ gg1,
    const float* __restrict__ beg1, const float* __restrict__ wg2,
    const float* __restrict__ bg2, float* __restrict__ ws) {
  __shared__ float ssum[64], ssq[64];
  const int t = threadIdx.x, lane = t & 63, w = t >> 6;
  if (t < 64) { ssum[t] = 0.0f; ssq[t] = 0.0f; }
  const float invN = 1.0f / (float)N_NODES;
  float s1 = ws[OFF_GS1SUM + lane], q1 = ws[OFF_GS1SQ + lane];
  float m1 = s1 * invN, v1 = q1 * invN - m1 * m1;
  float a1 = gg1[lane] * rsqrtf(v1 + BN_EPS);
  float c1 = beg1[lane] - a1 * m1;
  const float bcol = bg1[lane], b2col = bg2[lane];
  __syncthreads();
  const int nb = blockIdx.x * 16 + w * 4;
  float x[4], tg1[4], hg[4], acc[4];
#pragma unroll
  for (int u = 0; u < 4; u++) {
    x[u] = (lane < 48) ? geom[(nb + u) * 48 + lane] : 0.0f;
    tg1[u] = bcol;
  }
#pragma unroll 16
  for (int k = 0; k < 48; k++) {
    float wvv = wg1[k * 64 + lane];
#pragma unroll
    for (int u = 0; u < 4; u++) tg1[u] = fmaf(__shfl(x[u], k), wvv, tg1[u]);
  }
#pragma unroll
  for (int u = 0; u < 4; u++) {
    hg[u] = silu_(fmaf(a1, tg1[u], c1));
    acc[u] = b2col;
  }
#pragma unroll 16
  for (int k = 0; k < 64; k++) {
    float wvv = wg2[k * 64 + lane];
#pragma unroll
    for (int u = 0; u < 4; u++) acc[u] = fmaf(__shfl(hg[u], k), wvv, acc[u]);
  }
  float bs = 0.0f, bq = 0.0f;
#pragma unroll
  for (int u = 0; u < 4; u++) {
    ws[OFF_TG2 + (nb + u) * 64 + lane] = acc[u];
    bs += acc[u]; bq += acc[u] * acc[u];
  }
  atomicAdd(&ssum[lane], bs);
  atomicAdd(&ssq[lane], bq);
  __syncthreads();
  if (t < 64) {
    atomicAdd(ws + OFF_GS2SUM + t, ssum[t]);
    atomicAdd(ws + OFF_GS2SQ + t, ssq[t]);
  }
}

__global__ __launch_bounds__(256) void k_fuse1(const float* __restrict__ wf1,
                                               const float* __restrict__ bf1,
                                               const float* __restrict__ gg2,
                                               const float* __restrict__ beg2,
                                               float* __restrict__ ws) {
  __shared__ float ssum[128], ssq[128];
  const int t = threadIdx.x, lane = t & 63, w = t >> 6;
  if (t < 128) { ssum[t] = 0.0f; ssq[t] = 0.0f; }
  const float invN = 1.0f / (float)N_NODES;
  float s2 = ws[OFF_GS2SUM + lane], q2 = ws[OFF_GS2SQ + lane];
  float mg = s2 * invN, vg = q2 * invN - mg * mg;
  float ag = gg2[lane] * rsqrtf(vg + BN_EPS);
  float cg_ = beg2[lane] - ag * mg;
  const float bA = bf1[lane], bB = bf1[64 + lane];
  __syncthreads();
  const int nb = blockIdx.x * 16 + w * 4;
  float xa[4], xb[4], xg[4], acc1[4], acc2[4];
#pragma unroll
  for (int u = 0; u < 4; u++) {
    int n = nb + u;
    xa[u] = ws[OFF_NODE + n * 128 + lane];
    xb[u] = ws[OFF_NODE + n * 128 + 64 + lane];
    xg[u] = fmaf(ag, ws[OFF_TG2 + n * 64 + lane], cg_);
    acc1[u] = bA; acc2[u] = bB;
  }
#pragma unroll 16
  for (int k = 0; k < 64; k++) {
    float w1v = wf1[k * 128 + lane], w2v = wf1[k * 128 + 64 + lane];
#pragma unroll
    for (int u = 0; u < 4; u++) {
      float xk = __shfl(xa[u], k);
      acc1[u] = fmaf(xk, w1v, acc1[u]);
      acc2[u] = fmaf(xk, w2v, acc2[u]);
    }
  }
#pragma unroll 16
  for (int k = 0; k < 64; k++) {
    float w1v = wf1[(64 + k) * 128 + lane], w2v = wf1[(64 + k) * 128 + 64 + lane];
#pragma unroll
    for (int u = 0; u < 4; u++) {
      float xk = __shfl(xb[u], k);
      acc1[u] = fmaf(xk, w1v, acc1[u]);
      acc2[u] = fmaf(xk, w2v, acc2[u]);
    }
  }
#pragma unroll 16
  for (int k = 0; k < 64; k++) {
    float w1v = wf1[(128 + k) * 128 + lane], w2v = wf1[(128 + k) * 128 + 64 + lane];
#pragma unroll
    for (int u = 0; u < 4; u++) {
      float xk = __shfl(xg[u], k);
      acc1[u] = fmaf(xk, w1v, acc1[u]);
      acc2[u] = fmaf(xk, w2v, acc2[u]);
    }
  }
  float sA = 0, qA = 0, sB = 0, qB = 0;
#pragma unroll
  for (int u = 0; u < 4; u++) {
    int n = nb + u;
    ws[OFF_TF1 + n * 128 + lane] = acc1[u];
    ws[OFF_TF1 + n * 128 + 64 + lane] = acc2[u];
    sA += acc1[u]; qA += acc1[u] * acc1[u];
    sB += acc2[u]; qB += acc2[u] * acc2[u];
  }
  atomicAdd(&ssum[lane], sA); atomicAdd(&ssq[lane], qA);
  atomicAdd(&ssum[64 + lane], sB); atomicAdd(&ssq[64 + lane], qB);
  __syncthreads();
  if (t < 128) {
    atomicAdd(ws + OFF_FS1SUM + t, ssum[t]);
    atomicAdd(ws + OFF_FS1SQ + t, ssq[t]);
  }
}

__global__ __launch_bounds__(256) void k_fuse2(const float* __restrict__ wf2,
                                               const float* __restrict__ bf2,
                                               const float* __restrict__ gf1,
                                               const float* __restrict__ bef1,
                                               float* __restrict__ ws) {
  __shared__ float ssum[128], ssq[128];
  const int t = threadIdx.x, lane = t & 63, w = t >> 6;
  if (t < 128) { ssum[t] = 0.0f; ssq[t] = 0.0f; }
  const float invN = 1.0f / (float)N_NODES;
  float sA_ = ws[OFF_FS1SUM + lane], qA_ = ws[OFF_FS1SQ + lane];
  float mA = sA_ * invN, vA = qA_ * invN - mA * mA;
  float aA = gf1[lane] * rsqrtf(vA + BN_EPS);
  float cA = bef1[lane] - aA * mA;
  float sB_ = ws[OFF_FS1SUM + 64 + lane], qB_ = ws[OFF_FS1SQ + 64 + lane];
  float mB = sB_ * invN, vB = qB_ * invN - mB * mB;
  float aB = gf1[64 + lane] * rsqrtf(vB + BN_EPS);
  float cB = bef1[64 + lane] - aB * mB;
  const float b1c = bf2[lane], b2c = bf2[64 + lane];
  __syncthreads();
  const int nb = blockIdx.x * 16 + w * 4;
  float ha[4], hb[4], acc1[4], acc2[4];
#pragma unroll
  for (int u = 0; u < 4; u++) {
    int n = nb + u;
    ha[u] = silu_(fmaf(aA, ws[OFF_TF1 + n * 128 + lane], cA));
    hb[u] = silu_(fmaf(aB, ws[OFF_TF1 + n * 128 + 64 + lane], cB));
    acc1[u] = b1c; acc2[u] = b2c;
  }
#pragma unroll 16
  for (int k = 0; k < 64; k++) {
    float w1v = wf2[k * 128 + lane], w2v = wf2[k * 128 + 64 + lane];
#pragma unroll
    for (int u = 0; u < 4; u++) {
      float xk = __shfl(ha[u], k);
      acc1[u] = fmaf(xk, w1v, acc1[u]);
      acc2[u] = fmaf(xk, w2v, acc2[u]);
    }
  }
#pragma unroll 16
  for (int k = 0; k < 64; k++) {
    float w1v = wf2[(64 + k) * 128 + lane], w2v = wf2[(64 + k) * 128 + 64 + lane];
#pragma unroll
    for (int u = 0; u < 4; u++) {
      float xk = __shfl(hb[u], k);
      acc1[u] = fmaf(xk, w1v, acc1[u]);
      acc2[u] = fmaf(xk, w2v, acc2[u]);
    }
  }
  float sA = 0, qA = 0, sB = 0, qB = 0;
#pragma unroll
  for (int u = 0; u < 4; u++) {
    int n = nb + u;
    ws[OFF_TF2 + n * 128 + lane] = acc1[u];
    ws[OFF_TF2 + n * 128 + 64 + lane] = acc2[u];
    sA += acc1[u]; qA += acc1[u] * acc1[u];
    sB += acc2[u]; qB += acc2[u] * acc2[u];
  }
  atomicAdd(&ssum[lane], sA); atomicAdd(&ssq[lane], qA);
  atomicAdd(&ssum[64 + lane], sB); atomicAdd(&ssq[64 + lane], qB);
  __syncthreads();
  if (t < 128) {
    atomicAdd(ws + OFF_FS2SUM + t, ssum[t]);
    atomicAdd(ws + OFF_FS2SQ + t, ssq[t]);
  }
}

__global__ __launch_bounds__(256) void k_final(const float* __restrict__ gf2,
                                               const float* __restrict__ bef2,
                                               const float* __restrict__ ws,
                                               float* __restrict__ out) {
  const int idx = blockIdx.x * 256 + threadIdx.x;
  const int base = idx * 4;
  if (base >= N_NODES * 128) return;
  const float invN = 1.0f / (float)N_NODES;
  const int c0 = base & 127;
  float4 v = *(const float4*)(ws + OFF_TF2 + base);
  float vv[4] = {v.x, v.y, v.z, v.w}, r[4];
#pragma unroll
  for (int j = 0; j < 4; j++) {
    int c = c0 + j;
    float s = ws[OFF_FS2SUM + c], q = ws[OFF_FS2SQ + c];
    float m = s * invN, var = q * invN - m * m;
    float a = gf2[c] * rsqrtf(var + BN_EPS);
    r[j] = fmaf(a, vv[j] - m, bef2[c]);
  }
  *(float4*)(out + base) = make_float4(r[0], r[1], r[2], r[3]);
}

extern "C" void kernel_launch(void* const* d_in, const int* in_sizes, int n_in,
                              void* d_out, int out_size, void* d_ws, size_t ws_size,
                              hipStream_t stream) {
  const float* chem = (const float*)d_in[0];
  const float* geom = (const float*)d_in[1];
  const int* vids = (const int*)d_in[2];
  const float* w_c1 = (const float*)d_in[3];  const float* b_c1 = (const float*)d_in[4];
  const float* g_c1 = (const float*)d_in[5];  const float* be_c1 = (const float*)d_in[6];
  const float* w_c2 = (const float*)d_in[7];  const float* b_c2 = (const float*)d_in[8];
  const float* g_c2 = (const float*)d_in[9];  const float* be_c2 = (const float*)d_in[10];
  const float* w_g1 = (const float*)d_in[11]; const float* b_g1 = (const float*)d_in[12];
  const float* g_g1 = (const float*)d_in[13]; const float* be_g1 = (const float*)d_in[14];
  const float* w_g2 = (const float*)d_in[15]; const float* b_g2 = (const float*)d_in[16];
  const float* g_g2 = (const float*)d_in[17]; const float* be_g2 = (const float*)d_in[18];
  const float* w_f1 = (const float*)d_in[19]; const float* b_f1 = (const float*)d_in[20];
  const float* g_f1 = (const float*)d_in[21]; const float* be_f1 = (const float*)d_in[22];
  const float* w_f2 = (const float*)d_in[23]; const float* b_f2 = (const float*)d_in[24];
  const float* g_f2 = (const float*)d_in[25]; const float* be_f2 = (const float*)d_in[26];
  float* ws = (float*)d_ws;
  float* out = (float*)d_out;

  // zero Gram matrices + stats + node accumulator
  hipMemsetAsync(d_ws, 0, (size_t)(OFF_NODE + N_NODES * 128) * sizeof(float), stream);

  k_prep<<<dim3(160), dim3(256), 0, stream>>>(w_c1, w_c2, ws);
  k_xstats<<<dim3(1250), dim3(256), 0, stream>>>(chem, ws);
  k_bn1<<<dim3(128), dim3(64), 0, stream>>>(b_c1, g_c1, be_c1, ws);
  k_h<<<dim3(1250), dim3(256), 0, stream>>>(chem, ws);
  k_bn2<<<dim3(256), dim3(128), 0, stream>>>(b_c2, g_c2, be_c2, ws);
  k_scatter<<<dim3(1563), dim3(256), 0, stream>>>(chem, vids, ws);
  k_geom_stats1<<<dim3(3125), dim3(256), 0, stream>>>(geom, w_g1, b_g1, ws);
  k_geom_main<<<dim3(3125), dim3(256), 0, stream>>>(geom, w_g1, b_g1, g_g1, be_g1, w_g2, b_g2, ws);
  k_fuse1<<<dim3(3125), dim3(256), 0, stream>>>(w_f1, b_f1, g_g2, be_g2, ws);
  k_fuse2<<<dim3(3125), dim3(256), 0, stream>>>(w_f2, b_f2, g_f1, be_f1, ws);
  k_final<<<dim3(6250), dim3(256), 0, stream>>>(g_f2, be_f2, ws, out);
}